// Round 20
// baseline (232.016 us; speedup 1.0000x reference)
//
#include <hip/hip_runtime.h>
#include <hip/hip_bf16.h>
#include <math.h>

#define BN_EPS 1e-3f
#define LOG2E 1.44269504088896f

constexpr int Bn = 4, Hn = 64, Wn = 64, CIN = 512, CI = 128;
constexpr int HWn = Hn * Wn;        // 4096
constexpr int NPIX = Bn * HWn;      // 16384
constexpr int COn = 19;
constexpr int XSL = 66;             // conv page slots (64 px + 2 halo)
constexpr int XPG = XSL * 16;       // 1056 elements per (row,chunk) page

struct F8 { float4 lo, hi; };

__device__ __forceinline__ F8 f8zero() {
    F8 r; r.lo = make_float4(0.f,0.f,0.f,0.f); r.hi = make_float4(0.f,0.f,0.f,0.f); return r;
}
__device__ __forceinline__ void fma8(F8 &acc, float a, const float4 &wlo, const float4 &whi) {
    acc.lo.x = fmaf(a, wlo.x, acc.lo.x);
    acc.lo.y = fmaf(a, wlo.y, acc.lo.y);
    acc.lo.z = fmaf(a, wlo.z, acc.lo.z);
    acc.lo.w = fmaf(a, wlo.w, acc.lo.w);
    acc.hi.x = fmaf(a, whi.x, acc.hi.x);
    acc.hi.y = fmaf(a, whi.y, acc.hi.y);
    acc.hi.z = fmaf(a, whi.z, acc.hi.z);
    acc.hi.w = fmaf(a, whi.w, acc.hi.w);
}

// ---- MFMA helpers -----------------------------------------------------------
typedef __attribute__((ext_vector_type(8)))  short    short8;  // 8 bf16
typedef __attribute__((ext_vector_type(8)))  _Float16 half8;   // 8 fp16
typedef __attribute__((ext_vector_type(16))) float    f32x16;

__device__ __forceinline__ f32x16 f16z() {
    f32x16 z;
    #pragma unroll
    for (int i = 0; i < 16; ++i) z[i] = 0.f;
    return z;
}
// fp32 -> bf16 (RNE), integer ops (prep-only)
__device__ __forceinline__ unsigned f2b(float f) {
    union { float f; unsigned u; } c; c.f = f;
    return (c.u + 0x7FFFu + ((c.u >> 16) & 1u)) >> 16;
}
__device__ __forceinline__ unsigned pack2(float lo, float hi) {
    return (f2b(hi) << 16) | f2b(lo);
}
// cvt-based bf16 pair pack (hot path)
__device__ __forceinline__ unsigned pkb2(float a, float b) {
    __hip_bfloat16 ha = __float2bfloat16(a);
    __hip_bfloat16 hb = __float2bfloat16(b);
    return ((unsigned)*(unsigned short*)&hb << 16) | *(unsigned short*)&ha;
}
// split (a,b) into packed bf16 hi words + bf16 lo residuals (prep-only)
__device__ __forceinline__ void split2(float a, float b, unsigned &hi, unsigned &lo) {
    const unsigned ha = f2b(a), hb = f2b(b);
    union { unsigned u; float f; } ua, ub; ua.u = ha << 16; ub.u = hb << 16;
    hi = (hb << 16) | ha;
    lo = pack2(a - ua.f, b - ub.f);
}
// pack two fp32 -> packed fp16 pair
__device__ __forceinline__ unsigned pkh2(float a, float b) {
    union { _Float16 h; unsigned short u; } ca, cb;
    ca.h = (_Float16)a; cb.h = (_Float16)b;
    return ((unsigned)cb.u << 16) | ca.u;
}

// ---------------- prep: weights -> fp16 single plane, co-major ---------------
__global__ __launch_bounds__(256)
void k_prep_w(const float* __restrict__ w5a, const float* __restrict__ w5c,
              const float* __restrict__ w51, const float* __restrict__ w52,
              char* __restrict__ wt1F, char* __restrict__ wt2aF, char* __restrict__ wt2bF)
{
    int idx = blockIdx.x * 256 + threadIdx.x;
    if (idx < 589824) {                       // 32*9*256*8 pairs
        const int jp = idx & 7, co = (idx >> 3) & 255, ct = idx >> 11; // ct=c*9+tap
        const int tap = ct % 9, c = ct / 9;
        const float* src = (co < 128) ? w5a : w5c;
        const int coc = co & 127;
        const int ci = c*16 + jp*2;
        const float a = src[((size_t)tap*CIN + ci)*CI + coc];
        const float b = src[((size_t)tap*CIN + ci + 1)*CI + coc];
        const int L = co*32 + jp*4;
        *(unsigned*)(wt1F + (size_t)ct*8192 + L) = pkh2(a, b);
    } else {
        int k = idx - 589824;                 // 2 * 8*9*128*8 pairs
        if (k >= 147456) return;
        const float* src = (k < 73728) ? w51 : w52;
        char* dstF = (k < 73728) ? wt2aF : wt2bF;
        if (k >= 73728) k -= 73728;
        const int jp = k & 7, co = (k >> 3) & 127, ct = k >> 10; // ct=c*9+tap
        const int tap = ct % 9, c = ct / 9;
        const int ci = c*16 + jp*2;
        const float a = src[((size_t)tap*CI + ci)*CI + co];
        const float b = src[((size_t)tap*CI + ci + 1)*CI + co];
        const int L = co*32 + jp*4;
        *(unsigned*)(dstF + (size_t)ct*4096 + L) = pkh2(a, b);
    }
}

// ---------------- prep: BN -> folded scale/bias tables -----------------------
__global__ __launch_bounds__(256)
void k_prep_bn(const float* g1, const float* b1, const float* m1, const float* v1,
               const float* g2, const float* b2, const float* m2, const float* v2,
               const float* g3, const float* b3, const float* m3, const float* v3,
               const float* g4, const float* b4, const float* m4, const float* v4,
               float* bnAs, float* bnAb, float* bnBs, float* bnBb)
{
    const int t = threadIdx.x, c = t & 127;
    {
        const float *g = (t < 128) ? g1 : g2, *b = (t < 128) ? b1 : b2;
        const float *m = (t < 128) ? m1 : m2, *v = (t < 128) ? v1 : v2;
        const float s = g[c] * rsqrtf(v[c] + BN_EPS);
        bnAs[t] = s; bnAb[t] = b[c] - m[c]*s;
    }
    {
        const float *g = (t < 128) ? g3 : g4, *b = (t < 128) ? b3 : b4;
        const float *m = (t < 128) ? m3 : m4, *v = (t < 128) ? v3 : v4;
        const float s = g[c] * rsqrtf(v[c] + BN_EPS);
        bnBs[t] = s; bnBb[t] = b[c] - m[c]*s;
    }
}

// ------- prep: x -> fp16 halo'd conv layout [row][32 chunk][66 slot][16 ch] --
__global__ __launch_bounds__(256)
void k_prep_x(const float* __restrict__ x, _Float16* __restrict__ xcv)
{
    __shared__ float Xl[16*520];
    const int t = threadIdx.x;
    const int pb = blockIdx.x * 16;           // 1024 blocks; 16 px of one row
    #pragma unroll
    for (int i = 0; i < 8; ++i) {
        const int u = t + i*256;
        const int px = u >> 7, c4 = (u & 127) * 4;
        *(float4*)&Xl[px*520 + c4] = *(const float4*)&x[(size_t)(pb + px)*CIN + c4];
    }
    __syncthreads();
    const int rowg = pb >> 6, pixb = pb & 63;
    #pragma unroll
    for (int i = 0; i < 8; ++i) {
        const int u = t + i*256;
        const int chunk = u >> 6, rem = u & 63;
        const int pl = rem >> 2, u4 = rem & 3;
        const float* src = &Xl[pl*520 + chunk*16 + u4*4];
        uint2 v;
        v.x = pkh2(src[0], src[1]);
        v.y = pkh2(src[2], src[3]);
        *(uint2*)&xcv[(((size_t)rowg*32 + chunk)*XSL + (pixb + pl + 1))*16 + u4*4] = v;
    }
    // zero the halo slots (0 and 65) of every chunk page of this row
    if (pixb == 0 && t < 64) {
        const int chunk = t >> 1, sl = (t & 1) * 65;
        uint4* dst = (uint4*)&xcv[(((size_t)rowg*32 + chunk)*XSL + sl)*16];
        uint4 z; z.x = 0u; z.y = 0u; z.z = 0u; z.w = 0u;
        dst[0] = z; dst[1] = z;
    }
}

// ---- zero halo slots of saf_h/scf_h (run AFTER conv1: region aliases xcv) ---
__global__ __launch_bounds__(256)
void k_zhalo(_Float16* __restrict__ saf_h, _Float16* __restrict__ scf_h)
{
    const int idx = blockIdx.x * 256 + threadIdx.x;   // 8192 units
    if (idx >= 8192) return;
    _Float16* arr = (idx & 4096) ? scf_h : saf_h;
    const int rem = idx & 4095;
    const int row = rem >> 4, chunk = (rem >> 1) & 7, sl = (rem & 1) * 65;
    uint4* dst = (uint4*)&arr[(((size_t)row*8 + chunk)*XSL + sl)*16];
    uint4 z; z.x = 0u; z.y = 0u; z.z = 0u; z.w = 0u;
    dst[0] = z; dst[1] = z;
}

// ---------------- MFMA 3x3 conv, fp16, 4-row block, W+X LDS-staged -----------
template<int NCHNK, int NCOTOT, int WCOBASE>
__global__ __launch_bounds__(512)
void k_convr(const _Float16* __restrict__ xcv0, const _Float16* __restrict__ xcv1,
             const _Float16* __restrict__ wtF0, const _Float16* __restrict__ wtF1,
             const float* __restrict__ bnS, const float* __restrict__ bnBi,
             float* __restrict__ out0, float* __restrict__ out1)
{
    constexpr int WU4  = 1152;                // 9 taps * 128 u4 (18432 B)
    constexpr int XU4  = 792;                 // 6 pages * 132 u4 (12672 B)
    constexpr int BUFB = (WU4 + XU4) * 16;    // 31104 B per buffer
    __shared__ __align__(16) char Ls[2*BUFB];

    const int t     = threadIdx.x;
    const int wgid  = blockIdx.x;             // 256
    const int slice = wgid & 3;
    const int rg    = wgid >> 2;              // 0..63 (4-row group)
    const int sel   = slice >> 1;
    const int ch2   = slice & 1;
    const _Float16* xcv = sel ? xcv1 : xcv0;
    const _Float16* wtF = sel ? wtF1 : wtF0;
    float* dst = sel ? out1 : out0;

    const int hh0 = (rg*4) & 63;              // row-in-image of group start
    const int l = t & 63, w = t >> 6;
    const int lo5 = l & 31, hf = l >> 5;
    const int r = w >> 1, mi = w & 1;
    const int cobase0 = WCOBASE*sel + ch2*64;

    // ---- hoisted stage decode: 1944 u4 units, 4 slots/thread ----
    bool sAct[4]; bool sIsW[4]; int sDst[4]; size_t sSrc[4]; unsigned sStr[4];
    #pragma unroll
    for (int i = 0; i < 4; ++i) {
        const int u = t + i*512;
        sAct[i] = false; sIsW[i] = false; sDst[i] = -1; sSrc[i] = 0; sStr[i] = 0;
        if (u < WU4) {
            const int tap = u >> 7, rem = u & 127;
            const int co = rem >> 1, whf = rem & 1;
            sAct[i] = true; sIsW[i] = true;
            sSrc[i] = (size_t)(tap*NCOTOT + cobase0 + co)*32 + whf*16;
            sStr[i] = (unsigned)(9*NCOTOT*32);
            sDst[i] = (tap*128 + whf*64 + co) * 16;
        } else if (u < WU4 + XU4) {
            const int j = u - WU4;
            const int page = j / 132, rem132 = j - page*132;
            const int slot = rem132 >> 1, xhf = rem132 & 1;
            const int hin = hh0 + page - 1;               // row in image
            sAct[i] = (hin >= 0 && hin < Hn);
            const int gr = rg*4 + page - 1;               // global row
            sSrc[i] = (size_t)gr*NCHNK*2112 + (size_t)(slot*32 + xhf*16);
            sStr[i] = 2112u;
            sDst[i] = WU4*16 + page*2112 + ((slot*32 + xhf*16) ^ ((slot & 7) << 4));
        }
    }
    // hoisted compute X offsets (dy, dx) for this wave's (r, mi)
    int xoff[3][3];
    #pragma unroll
    for (int dy = 0; dy < 3; ++dy)
        #pragma unroll
        for (int dx = 0; dx < 3; ++dx) {
            const int s = mi*32 + lo5 + dx;
            xoff[dy][dx] = WU4*16 + (r + dy)*2112 + ((s*32 + hf*16) ^ ((s & 7) << 4));
        }

    f32x16 acc[2];
    acc[0] = f16z(); acc[1] = f16z();

    uint4 xr[4];
    auto loadS = [&](int c) {
        #pragma unroll
        for (int i = 0; i < 4; ++i) {
            uint4 v; v.x = 0u; v.y = 0u; v.z = 0u; v.w = 0u;
            if (sAct[i]) {
                const char* base = sIsW[i] ? (const char*)wtF : (const char*)xcv;
                v = *(const uint4*)(base + sSrc[i] + (size_t)c*sStr[i]);
            }
            xr[i] = v;
        }
    };

    loadS(0);
    int p = 0;
    for (int c = 0; c < NCHNK; ++c) {
        char* Lp = Ls + p*BUFB;
        #pragma unroll
        for (int i = 0; i < 4; ++i)
            if (sDst[i] >= 0) *(uint4*)(Lp + sDst[i]) = xr[i];
        __syncthreads();
        if (c + 1 < NCHNK) loadS(c + 1);
        // ---- compute: 9 taps, 2 co-tiles each ----
        #pragma unroll
        for (int dy = 0; dy < 3; ++dy)
            #pragma unroll
            for (int dx = 0; dx < 3; ++dx) {
                const half8 xf = *(const half8*)(Lp + xoff[dy][dx]);
                const half8 w0 = *(const half8*)(Lp + ((dy*3 + dx)*128 + hf*64 + lo5)*16);
                const half8 w1 = *(const half8*)(Lp + ((dy*3 + dx)*128 + hf*64 + 32 + lo5)*16);
                acc[0] = __builtin_amdgcn_mfma_f32_32x32x16_f16(w0, xf, acc[0], 0, 0, 0);
                acc[1] = __builtin_amdgcn_mfma_f32_32x32x16_f16(w1, xf, acc[1], 0, 0, 0);
            }
        p ^= 1;
    }
    // ---- epilogue: folded BN + ReLU (fp32 out) ----
    const int px = mi*32 + lo5;
    const size_t pg = (size_t)(rg*4 + r)*Wn + px;
    #pragma unroll
    for (int cot = 0; cot < 2; ++cot)
        #pragma unroll
        for (int rr = 0; rr < 16; ++rr) {
            const int crow = (rr & 3) + 8*(rr >> 2) + 4*hf;
            const int och = ch2*64 + cot*32 + crow;
            const int bnidx = sel*128 + och;
            dst[pg*CI + och] = fmaxf(fmaf(acc[cot][rr], bnS[bnidx], bnBi[bnidx]), 0.f);
        }
}

// ---------------- K2a: q,k 1x1 conv -> bf16 (q pre-scaled by log2e) ----------
__global__ __launch_bounds__(256)
void k_qk(const float* __restrict__ feat1,
          const float* __restrict__ wq, const float* __restrict__ bq,
          const float* __restrict__ wk, const float* __restrict__ bk,
          __hip_bfloat16* __restrict__ qb, __hip_bfloat16* __restrict__ kb)
{
    __shared__ float Al[64*129];
    __shared__ __align__(16) float Wl[128*32];
    const int t = threadIdx.x;
    const int pb = blockIdx.x * 64;
    for (int idx = t; idx < 64*128; idx += 256) {
        const int p = idx >> 7, ci = idx & 127;
        Al[p*129 + ci] = feat1[(size_t)(pb + p)*CI + ci];
    }
    for (int idx = t; idx < 128*32; idx += 256) {
        const int ci = idx >> 5, c = idx & 31;
        Wl[idx] = (c < 16) ? wq[ci*16 + c] : wk[ci*16 + (c - 16)];
    }
    __syncthreads();
    const int p = t & 63, cg = t >> 6, co = cg * 8;
    F8 acc = f8zero();
    #pragma unroll 8
    for (int ci = 0; ci < 128; ++ci) {
        const float a = Al[p*129 + ci];
        const float4 wlo = *(const float4*)&Wl[ci*32 + co];
        const float4 whi = *(const float4*)&Wl[ci*32 + co + 4];
        fma8(acc, a, wlo, whi);
    }
    const float* af = (const float*)&acc;
    #pragma unroll
    for (int j = 0; j < 8; ++j) {
        const int c = co + j;
        if (c < 16) qb[(size_t)(pb + p)*16 + c]        = __float2bfloat16((af[j] + bq[c]) * LOG2E);
        else        kb[(size_t)(pb + p)*16 + (c - 16)] = __float2bfloat16(af[j] + bk[c - 16]);
    }
}

// ---------------- K2b: v 1x1 conv -> bf16 COALESCED [b][key/16][c][16key] ----
__global__ __launch_bounds__(256)
void k_v(const float* __restrict__ feat1, const float* __restrict__ wv,
         const float* __restrict__ bv, __hip_bfloat16* __restrict__ vbT)
{
    __shared__ float Al[32*129];
    __shared__ __align__(16) float Wl[64*128];
    const int t = threadIdx.x;
    const int pb = blockIdx.x * 32;
    for (int idx = t; idx < 32*128; idx += 256) {
        const int p = idx >> 7, ci = idx & 127;
        Al[p*129 + ci] = feat1[(size_t)(pb + p)*CI + ci];
    }
    const int px = t & 15, co = (t >> 4) * 8;
    F8 acc0 = f8zero(), acc1 = f8zero();
    for (int ch = 0; ch < 2; ++ch) {
        __syncthreads();
        #pragma unroll
        for (int r = 0; r < 8; ++r) {
            const int i4 = t + r*256;
            const int kk = i4 >> 5, c4 = (i4 & 31) * 4;
            *(float4*)&Wl[kk*128 + c4] = *(const float4*)&wv[(size_t)(ch*64 + kk)*CI + c4];
        }
        __syncthreads();
        #pragma unroll 4
        for (int kk = 0; kk < 64; ++kk) {
            const float a0 = Al[px*129 + ch*64 + kk];
            const float a1 = Al[(px+16)*129 + ch*64 + kk];
            const float4 wlo = *(const float4*)&Wl[kk*128 + co];
            const float4 whi = *(const float4*)&Wl[kk*128 + co + 4];
            fma8(acc0, a0, wlo, whi);
            fma8(acc1, a1, wlo, whi);
        }
    }
    const int p0 = pb + px;
    const int bb = p0 / HWn, pin0 = p0 % HWn;
    const int k16a = pin0 >> 4, ko = pin0 & 15;
    const float* a0f = (const float*)&acc0;
    const float* a1f = (const float*)&acc1;
    #pragma unroll
    for (int j = 0; j < 8; ++j) {
        const int c = co + j;
        const size_t base = ((size_t)bb*256*CI*16) + (size_t)c*16 + ko;
        vbT[base + (size_t)k16a*CI*16]       = __float2bfloat16(a0f[j] + bv[c]);
        vbT[base + (size_t)(k16a + 1)*CI*16] = __float2bfloat16(a1f[j] + bv[c]);
    }
}

// ---------------- K3: PAM flash attention, 2-block K-split + 4-wave ----------
// Grid 1024: each q-tile handled by TWO blocks (K halves of 2048; each block
// 4 waves x 512 keys). Batch-pinned XCD swizzle kept. Block emits a
// NORMALIZED fp16 partial (o/s, bounded by |V|) + per-row LSE m+log2(s);
// k_pam_merge combines the two in log space. Doubles resident blocks/CU.
__global__ __launch_bounds__(256)
void k_pam(const __hip_bfloat16* __restrict__ qb, const __hip_bfloat16* __restrict__ kb,
           const __hip_bfloat16* __restrict__ vbT,
           _Float16* __restrict__ opart, float* __restrict__ lsep)
{
    __shared__ __align__(16) char pbuf[16896];   // Ppk[4][1024 u32] -> osum[32][132] f32
    __shared__ float msArr[4][32];
    __shared__ float ssArr[4][32];
    __shared__ float ssum[32];
    const int t  = threadIdx.x;
    const int wv = t >> 6, l = t & 63;
    const int lo5 = l & 31, h = l >> 5;
    unsigned* Ppk = (unsigned*)(pbuf + wv*4096);
    float* osum = (float*)pbuf;

    // batch-pinned XCD decode: 1024 blocks, 256/batch on 2 XCDs
    const int wgid = blockIdx.x;
    const int xcd  = wgid & 7;
    const int bb   = xcd >> 1;                       // batch
    const int u    = ((wgid >> 3) << 1) | (xcd & 1); // 0..255
    const int qt   = u >> 1;                         // q-tile 0..127
    const int kh   = u & 1;                          // K half
    const int q0   = bb*HWn + qt*32;
    const int part = ((bb*128 + qt) << 1) | kh;      // 0..1023
    const size_t jb = (size_t)bb * HWn;
    const __hip_bfloat16* vbB = vbT + (size_t)bb * 256 * CI * 16;

    const short8 qfrag = *(const short8*)&qb[(size_t)(q0 + lo5)*16 + 8*h];
    const f32x16 zro = f16z();

    f32x16 o[4];
    #pragma unroll
    for (int cb = 0; cb < 4; ++cb) o[cb] = f16z();

    float m_run = -1e30f, s_run = 0.f;

    const int kbeg = kh*2048 + wv*512, kend = kbeg + 512;
    short8 kf0 = *(const short8*)&kb[(jb + kbeg +      lo5)*16 + 8*h];
    short8 kf1 = *(const short8*)&kb[(jb + kbeg + 32 + lo5)*16 + 8*h];

    for (int k0 = kbeg; k0 < kend; k0 += 64) {
        short8 vf[4][4];
        #pragma unroll
        for (int s = 0; s < 4; ++s)
            #pragma unroll
            for (int cb = 0; cb < 4; ++cb)
                vf[s][cb] = *(const short8*)&vbB[
                    (((size_t)(k0 >> 4) + s)*CI + cb*32 + lo5)*16 + 8*h];

        f32x16 e0 = __builtin_amdgcn_mfma_f32_32x32x16_bf16(kf0, qfrag, zro, 0, 0, 0);
        f32x16 e1 = __builtin_amdgcn_mfma_f32_32x32x16_bf16(kf1, qfrag, zro, 0, 0, 0);

        // prefetch next tile's K fragments
        if (k0 + 64 < kend) {
            kf0 = *(const short8*)&kb[(jb + k0 + 64 +      lo5)*16 + 8*h];
            kf1 = *(const short8*)&kb[(jb + k0 + 64 + 32 + lo5)*16 + 8*h];
        }

        // tree max
        float mx8[8];
        #pragma unroll
        for (int r = 0; r < 8; ++r)
            mx8[r] = fmaxf(fmaxf(e0[r], e0[r+8]), fmaxf(e1[r], e1[r+8]));
        mx8[0] = fmaxf(mx8[0], mx8[4]);
        mx8[1] = fmaxf(mx8[1], mx8[5]);
        mx8[2] = fmaxf(mx8[2], mx8[6]);
        mx8[3] = fmaxf(mx8[3], mx8[7]);
        mx8[0] = fmaxf(mx8[0], mx8[2]);
        mx8[1] = fmaxf(mx8[1], mx8[3]);
        float mt = fmaxf(mx8[0], mx8[1]);
        mt = fmaxf(mt, __shfl_xor(mt, 32));

        if (__any(mt > m_run + 11.5416f)) {   // 8 * log2(e)
            const float mnew = fmaxf(m_run, mt);
            const float sc = exp2f(m_run - mnew);
            s_run *= sc;
            #pragma unroll
            for (int cb = 0; cb < 4; ++cb)
                #pragma unroll
                for (int r = 0; r < 16; ++r) o[cb][r] *= sc;
            m_run = mnew;
        }

        #pragma unroll
        for (int r = 0; r < 16; ++r) {
            e0[r] = exp2f(e0[r] - m_run);
            e1[r] = exp2f(e1[r] - m_run);
        }
        // tree sum
        {
            float s8[8];
            #pragma unroll
            for (int r = 0; r < 8; ++r)
                s8[r] = (e0[r] + e0[r+8]) + (e1[r] + e1[r+8]);
            s8[0] += s8[4]; s8[1] += s8[5]; s8[2] += s8[6]; s8[3] += s8[7];
            s8[0] += s8[2]; s8[1] += s8[3];
            s_run += s8[0] + s8[1];
        }

        #pragma unroll
        for (int r = 0; r < 16; r += 2) {
            const int pidx = ((r & 3) >> 1) + 4*(r >> 2) + 2*h;
            Ppk[pidx*32 + lo5]        = pkb2(e0[r], e0[r+1]);
            Ppk[(16 + pidx)*32 + lo5] = pkb2(e1[r], e1[r+1]);
        }
        #pragma unroll
        for (int s = 0; s < 4; ++s) {
            union { unsigned u[4]; short8 s8; } P;
            #pragma unroll
            for (int w = 0; w < 4; ++w)
                P.u[w] = Ppk[(s*8 + 4*h + w)*32 + lo5];
            #pragma unroll
            for (int cb = 0; cb < 4; ++cb)
                o[cb] = __builtin_amdgcn_mfma_f32_32x32x16_bf16(vf[s][cb], P.s8, o[cb], 0, 0, 0);
        }
    }

    // ---- publish per-wave (m, s) ----
    const float s_w = s_run + __shfl_xor(s_run, 32);
    if (h == 0) { msArr[wv][lo5] = m_run; ssArr[wv][lo5] = s_w; }
    __syncthreads();

    // ---- in-block merge across 4 waves ----
    float M = msArr[0][lo5];
    #pragma unroll
    for (int w = 1; w < 4; ++w) M = fmaxf(M, msArr[w][lo5]);
    float stot = 0.f;
    #pragma unroll
    for (int w = 0; w < 4; ++w) stot += exp2f(msArr[w][lo5] - M) * ssArr[w][lo5];
    if (wv == 0 && h == 0) {
        ssum[lo5] = stot;
        lsep[part*32 + lo5] = M + log2f(stot);   // block LSE
    }
    const float myscale = exp2f(m_run - M);
    #pragma unroll
    for (int cb = 0; cb < 4; ++cb)
        #pragma unroll
        for (int r = 0; r < 16; ++r) o[cb][r] *= myscale;

    for (int w = 0; w < 4; ++w) {
        if (wv == w) {
            #pragma unroll
            for (int cb = 0; cb < 4; ++cb)
                #pragma unroll
                for (int r = 0; r < 16; ++r) {
                    const int c = cb*32 + (r & 3) + 8*(r >> 2) + 4*h;
                    float* p = &osum[lo5*132 + c];
                    if (w == 0) *p = o[cb][r]; else *p += o[cb][r];
                }
        }
        __syncthreads();
    }

    // ---- store NORMALIZED fp16 partial (o/s, bounded by |V|) ----
    const int qloc = t >> 3, ch8 = t & 7;
    const float inv = 1.f / ssum[qloc];
    union { _Float16 hv[16]; uint4 u2[2]; } tmp;
    #pragma unroll
    for (int j = 0; j < 16; ++j)
        tmp.hv[j] = (_Float16)(osum[qloc*132 + ch8*16 + j] * inv);
    uint4* dsto = (uint4*)&opart[(size_t)part*4096 + qloc*128 + ch8*16];
    dsto[0] = tmp.u2[0];
    dsto[1] = tmp.u2[1];
}

// ---------------- K3b: merge two K-half partials + residual ------------------
__global__ __launch_bounds__(256)
void k_pam_merge(const _Float16* __restrict__ opart, const float* __restrict__ lsep,
                 const float* __restrict__ feat1, const float* __restrict__ gamma,
                 _Float16* __restrict__ saf_h)
{
    const int qg = blockIdx.x;              // 0..511 global q-tile
    const int t = threadIdx.x;
    const int qloc = t >> 3, ch8 = t & 7;
    const int p0 = qg*2, p1 = qg*2 + 1;
    const float l0 = lsep[p0*32 + qloc], l1 = lsep[p1*32 + qloc];
    const float L = fmaxf(l0, l1);
    const float w0 = exp2f(l0 - L), w1 = exp2f(l1 - L);
    const float inv = 1.f / (w0 + w1);
    const float g = gamma[0];
    const int pgl = qg*32 + qloc;           // global pixel row
    const int rowp = pgl >> 6, pixp = pgl & 63;
    const size_t gbase = (size_t)pgl*CI + ch8*16;
    const _Float16* s0 = &opart[(size_t)p0*4096 + qloc*128 + ch8*16];
    const _Float16* s1 = &opart[(size_t)p1*4096 + qloc*128 + ch8*16];
    union { _Float16 hv[16]; uint4 u[2]; } tmp;
    #pragma unroll
    for (int j = 0; j < 16; ++j) {
        const float ov = (w0*(float)s0[j] + w1*(float)s1[j]) * inv;
        tmp.hv[j] = (_Float16)(g*ov + feat1[gbase + j]);
    }
    uint4* dsth = (uint4*)&saf_h[(((size_t)rowp*8 + ch8)*XSL + (pixp + 1))*16];
    dsth[0] = tmp.u[0];
    dsth[1] = tmp.u[1];
}

// ---------------- K4x: transpose feat2 -> bf16 hi/lo [b][c][HW] --------------
__global__ __launch_bounds__(256)
void k_xpose(const float* __restrict__ feat2,
             char* __restrict__ f2TH, char* __restrict__ f2TL)
{
    __shared__ float Xl[64*129];
    const int t = threadIdx.x;
    const int pb = blockIdx.x * 64;
    const int bb = pb / HWn, pin = pb % HWn;
    for (int idx = t; idx < 64*128; idx += 256) {
        const int p = idx >> 7, ci = idx & 127;
        Xl[p*129 + ci] = feat2[(size_t)(pb + p)*CI + ci];
    }
    __syncthreads();
    const int c = t >> 1, half = t & 1;
    const size_t rowb = ((size_t)(bb*CI + c)*HWn + pin + half*32) * 2;
    #pragma unroll
    for (int j = 0; j < 16; ++j) {
        const float a = Xl[(half*32 + 2*j)*129 + c];
        const float b = Xl[(half*32 + 2*j + 1)*129 + c];
        unsigned hi, lo; split2(a, b, hi, lo);
        *(unsigned*)(f2TH + rowb + 4*j) = hi;
        *(unsigned*)(f2TL + rowb + 4*j) = lo;
    }
}

// ---------------- K4a: CAM energy via MFMA, split-K partials -----------------
__global__ __launch_bounds__(256)
void k_cam_energy_m(const char* __restrict__ f2TH, const char* __restrict__ f2TL,
                    float* __restrict__ epart)
{
    __shared__ __align__(16) char Vh[128*256];
    __shared__ __align__(16) char Vl[128*256];
    const int t = threadIdx.x;
    const int ks = blockIdx.x, bb = blockIdx.y;
    const int l = t & 63, w = t >> 6;
    const int lo5 = l & 31, hf = l >> 5;

    #pragma unroll
    for (int pass = 0; pass < 8; ++pass) {
        const int slot = pass*256 + t;
        const int c = slot >> 4, g = slot & 15;
        const size_t gaddr = ((size_t)(bb*CI + c)*HWn + ks*128)*2 + g*16;
        const int laddr = c*256 + ((g*16) ^ ((c & 15) << 4));
        *(float4*)(Vh + laddr) = *(const float4*)(f2TH + gaddr);
        *(float4*)(Vl + laddr) = *(const float4*)(f2TL + gaddr);
    }
    __syncthreads();

    f32x16 acc[4];
    #pragma unroll
    for (int nj = 0; nj < 4; ++nj) acc[nj] = f16z();
    const int cA = w*32 + lo5;
    const int swA = (cA & 15) << 4;

    #pragma unroll
    for (int kk = 0; kk < 8; ++kk) {
        const int kb = kk*32 + hf*16;
        const short8 ah = *(const short8*)(Vh + cA*256 + (kb ^ swA));
        const short8 al = *(const short8*)(Vl + cA*256 + (kb ^ swA));
        #pragma unroll
        for (int nj = 0; nj < 4; ++nj) {
            const int dB = nj*32 + lo5;
            const int swB = (dB & 15) << 4;
            const short8 bh = *(const short8*)(Vh + dB*256 + (kb ^ swB));
            const short8 bl = *(const short8*)(Vl + dB*256 + (kb ^ swB));
            acc[nj] = __builtin_amdgcn_mfma_f32_32x32x16_bf16(ah, bh, acc[nj], 0, 0, 0);
            acc[nj] = __builtin_amdgcn_mfma_f32_32x32x16_bf16(al, bh, acc[nj], 0, 0, 0);
            acc[nj] = __builtin_amdgcn_mfma_f32_32x32x16_bf16(ah, bl, acc[nj], 0, 0, 0);
        }
    }
    float* ep = epart + ((size_t)(bb*32 + ks)*CI)*CI;
    #pragma unroll
    for (int nj = 0; nj < 4; ++nj)
        #pragma unroll
        for (int r = 0; r < 16; ++r) {
            const int c = w*32 + (r & 3) + 8*(r >> 2) + 4*hf;
            ep[(size_t)c*CI + nj*32 + lo5] = acc[nj][r];
        }
}

// ---------------- K4b: fused reduce + max-subtract softmax -------------------
__global__ __launch_bounds__(64)
void k_cam_rs(const float* __restrict__ epart, float* __restrict__ att)
{
    const int lane = threadIdx.x;
    const int row = blockIdx.x;             // b*128 + c
    const int bb = row >> 7, c = row & 127;
    float2 e = make_float2(0.f, 0.f);
    for (int ks = 0; ks < 32; ++ks) {
        const float2 v = *(const float2*)&epart[
            ((size_t)(bb*32 + ks)*CI + c)*CI + lane*2];
        e.x += v.x; e.y += v.y;
    }
    float M = fmaxf(e.x, e.y);
    #pragma unroll
    for (int off = 32; off > 0; off >>= 1) M = fmaxf(M, __shfl_xor(M, off));
    const float en0 = M - e.x, en1 = M - e.y;
    float mx = fmaxf(en0, en1);
    #pragma unroll
    for (int off = 32; off > 0; off >>= 1) mx = fmaxf(mx, __shfl_xor(mx, off));
    const float p0 = __expf(en0 - mx), p1 = __expf(en1 - mx);
    float s = p0 + p1;
    #pragma unroll
    for (int off = 32; off > 0; off >>= 1) s += __shfl_xor(s, off);
    const float inv = 1.f / s;
    float2 o; o.x = p0*inv; o.y = p1*inv;
    *(float2*)&att[(size_t)row*CI + lane*2] = o;
}

// ---------------- K4c: CAM apply -> fp16 halo'd conv layout ------------------
__global__ __launch_bounds__(256)
void k_cam_apply(const float* __restrict__ feat2, const float* __restrict__ att,
                 const float* __restrict__ gamma, _Float16* __restrict__ scf_h)
{
    __shared__ float Xl[64*129];
    __shared__ __align__(16) float aT[128*64];
    const int t = threadIdx.x;
    const int pb = blockIdx.x * 64;
    const int bb = pb / HWn;
    const int ch = blockIdx.y * 64;
    for (int idx = t; idx < 64*128; idx += 256) {
        const int p = idx >> 7, ci = idx & 127;
        Xl[p*129 + ci] = feat2[(size_t)(pb + p)*CI + ci];
    }
    for (int idx = t; idx < 128*64; idx += 256) {
        const int d = idx >> 6, cc = idx & 63;
        aT[d*64 + cc] = att[((size_t)bb*CI + ch + cc)*CI + d];
    }
    __syncthreads();
    const int px = t & 63, cg = t >> 6;
    F8 accA = f8zero(), accB = f8zero();
    #pragma unroll 4
    for (int d = 0; d < 128; ++d) {
        const float xv = Xl[px*129 + d];
        const float* ap = &aT[d*64 + cg*16];
        const float4 a0 = *(const float4*)&ap[0];
        const float4 a1 = *(const float4*)&ap[4];
        const float4 a2 = *(const float4*)&ap[8];
        const float4 a3 = *(const float4*)&ap[12];
        fma8(accA, xv, a0, a1);
        fma8(accB, xv, a2, a3);
    }
    const float g = gamma[0];
    const float* fa = (const float*)&accA;
    const float* fb = (const float*)&accB;
    const int p0g = pb + px;
    const int rowA = p0g >> 6, pixA = p0g & 63;
    const int chunkA = (ch >> 4) + cg;
    const size_t baseA = (((size_t)rowA*8 + chunkA)*XSL + (pixA + 1))*16;
    #pragma unroll
    for (int j = 0; j < 8; ++j) {
        const int cA = ch + cg*16 + j;
        const int cB = cA + 8;
        scf_h[baseA + j]     = (_Float16)(g*fa[j] + Xl[px*129 + cA]);
        scf_h[baseA + 8 + j] = (_Float16)(g*fb[j] + Xl[px*129 + cB]);
    }
}

// ---------------- K7: final 1x1 conv (sum of two branches) -> out ------------
__global__ __launch_bounds__(256)
void k_final(const float* __restrict__ sa, const float* __restrict__ sc,
             const float* __restrict__ w8, float* __restrict__ out)
{
    __shared__ float Xl[64*129];
    __shared__ float w8l[128*COn];
    const int t = threadIdx.x;
    const int pb = blockIdx.x * 64;
    for (int idx = t; idx < 64*128; idx += 256) {
        const int p = idx >> 7, ci = idx & 127;
        const size_t gi = (size_t)(pb + p)*CI + ci;
        Xl[p*129 + ci] = sa[gi] + sc[gi];
    }
    for (int idx = t; idx < 128*COn; idx += 256) w8l[idx] = w8[idx];
    __syncthreads();
    for (int idx = t; idx < 64*COn; idx += 256) {
        const int p = idx / COn, co = idx - p*COn;
        float acc = 0.f;
        #pragma unroll 8
        for (int ci = 0; ci < 128; ++ci)
            acc = fmaf(Xl[p*129 + ci], w8l[ci*COn + co], acc);
        out[(size_t)(pb + p)*COn + co] = acc;
    }
}

extern "C" void kernel_launch(void* const* d_in, const int* in_sizes, int n_in,
                              void* d_out, int out_size, void* d_ws, size_t ws_size,
                              hipStream_t stream)
{
    const float* x    = (const float*)d_in[0];
    const float* w5a  = (const float*)d_in[1];
    const float* w5c  = (const float*)d_in[2];
    const float* wq   = (const float*)d_in[3];
    const float* bq   = (const float*)d_in[4];
    const float* wk   = (const float*)d_in[5];
    const float* bk   = (const float*)d_in[6];
    const float* wv   = (const float*)d_in[7];
    const float* bv   = (const float*)d_in[8];
    const float* pgam = (const float*)d_in[9];
    const float* cgam = (const float*)d_in[10];
    const float* w51  = (const float*)d_in[11];
    const float* w52  = (const float*)d_in[12];
    const float* w8   = (const float*)d_in[13];
    const float* bn1g = (const float*)d_in[14];
    const float* bn1b = (const float*)d_in[15];
    const float* bn1m = (const float*)d_in[16];
    const float* bn1v = (const float*)d_in[17];
    const float* bn2g = (const float*)d_in[18];
    const float* bn2b = (const float*)d_in[19];
    const float* bn2m = (const float*)d_in[20];
    const float* bn2v = (const float*)d_in[21];
    const float* bn3g = (const float*)d_in[22];
    const float* bn3b = (const float*)d_in[23];
    const float* bn3m = (const float*)d_in[24];
    const float* bn3v = (const float*)d_in[25];
    const float* bn4g = (const float*)d_in[26];
    const float* bn4b = (const float*)d_in[27];
    const float* bn4m = (const float*)d_in[28];
    const float* bn4v = (const float*)d_in[29];

    char* wsb = (char*)d_ws;
    float* feat1 = (float*)(wsb + 0);
    char*  f2TH  = wsb + 0;                     // 4 MB
    char*  f2TL  = wsb + 4194304;               // 4 MB
    float* feat2 = (float*)(wsb + 8388608);
    _Float16* xcv   = (_Float16*)(wsb + 16777216);   // 17,301,504 B
    _Float16* saf_h = (_Float16*)(wsb + 16777216);   // 4,325,376 B (post-conv1)
    _Float16* scf_h = (_Float16*)(wsb + 21102592);   // 4,325,376 B -> 25427968
    _Float16* opart = (_Float16*)(wsb + 25427968);   // 8,388,608 B (pam partials;
    float*    epart = (float*)(wsb + 25427968);      //  reused by CAM energy after)
    float* att  = (float*)(wsb + 33816576);          // 256 KB -> 34078720
    float* lsep = (float*)(wsb + 33816576);          // 128 KB (pam LSE; att reuses after)
    __hip_bfloat16* qb16 = (__hip_bfloat16*)(wsb + 34078720);  // 512 KB
    __hip_bfloat16* kb16 = (__hip_bfloat16*)(wsb + 34603008);  // 512 KB
    __hip_bfloat16* vbT  = (__hip_bfloat16*)(wsb + 35127296);  // 4 MB -> 39321600
    char* wt1F  = wsb + 39321600;               // 2359296 -> 41680896
    char* wt2aF = wsb + 41680896;               // 294912  -> 41975808
    char* wt2bF = wsb + 41975808;               // 294912  -> 42270720
    float* bnAs = (float*)(wsb + 42270720);
    float* bnAb = (float*)(wsb + 42271744);
    float* bnBs = (float*)(wsb + 42272768);
    float* bnBb = (float*)(wsb + 42273792);     // high-water 42274816
    float* sa_conv = feat1;
    float* sc_conv = feat2;
    float* out  = (float*)d_out;

    k_prep_w<<<dim3(2880), 256, 0, stream>>>(w5a, w5c, w51, w52, wt1F, wt2aF, wt2bF);
    k_prep_bn<<<dim3(1), 256, 0, stream>>>(bn1g, bn1b, bn1m, bn1v, bn2g, bn2b, bn2m, bn2v,
                                           bn3g, bn3b, bn3m, bn3v, bn4g, bn4b, bn4m, bn4v,
                                           bnAs, bnAb, bnBs, bnBb);
    k_prep_x<<<dim3(1024), 256, 0, stream>>>(x, xcv);
    k_convr<32, 256, 128><<<dim3(256), 512, 0, stream>>>(
        xcv, xcv, (const _Float16*)wt1F, (const _Float16*)wt1F, bnAs, bnAb, feat1, feat2);
    k_zhalo<<<dim3(32), 256, 0, stream>>>(saf_h, scf_h);   // after conv1: aliases xcv
    k_qk<<<dim3(NPIX/64), 256, 0, stream>>>(feat1, wq, bq, wk, bk, qb16, kb16);
    k_v<<<dim3(NPIX/32), 256, 0, stream>>>(feat1, wv, bv, vbT);
    k_pam<<<dim3(1024), 256, 0, stream>>>(qb16, kb16, vbT, opart, lsep);
    k_pam_merge<<<dim3(512), 256, 0, stream>>>(opart, lsep, feat1, pgam, saf_h);
    k_xpose<<<dim3(NPIX/64), 256, 0, stream>>>(feat2, f2TH, f2TL);
    k_cam_energy_m<<<dim3(32, Bn), 256, 0, stream>>>(f2TH, f2TL, epart);
    k_cam_rs<<<dim3(Bn*CI), 64, 0, stream>>>(epart, att);
    k_cam_apply<<<dim3(NPIX/64, 2), 256, 0, stream>>>(feat2, att, cgam, scf_h);
    k_convr<8, 128, 0><<<dim3(256), 512, 0, stream>>>(
        saf_h, scf_h, (const _Float16*)wt2aF, (const _Float16*)wt2bF,
        bnBs, bnBb, sa_conv, sc_conv);
    k_final<<<dim3(NPIX/64), 256, 0, stream>>>(sa_conv, sc_conv, w8, out);
}

// Round 22
// 208.892 us; speedup vs baseline: 1.1107x; 1.1107x over previous
//
#include <hip/hip_runtime.h>
#include <hip/hip_bf16.h>
#include <math.h>

#define BN_EPS 1e-3f
#define LOG2E 1.44269504088896f

constexpr int Bn = 4, Hn = 64, Wn = 64, CIN = 512, CI = 128;
constexpr int HWn = Hn * Wn;        // 4096
constexpr int NPIX = Bn * HWn;      // 16384
constexpr int COn = 19;
constexpr int XSL = 66;             // conv page slots (64 px + 2 halo)
constexpr int XPG = XSL * 16;       // 1056 elements per (row,chunk) page

struct F8 { float4 lo, hi; };

__device__ __forceinline__ F8 f8zero() {
    F8 r; r.lo = make_float4(0.f,0.f,0.f,0.f); r.hi = make_float4(0.f,0.f,0.f,0.f); return r;
}
__device__ __forceinline__ void fma8(F8 &acc, float a, const float4 &wlo, const float4 &whi) {
    acc.lo.x = fmaf(a, wlo.x, acc.lo.x);
    acc.lo.y = fmaf(a, wlo.y, acc.lo.y);
    acc.lo.z = fmaf(a, wlo.z, acc.lo.z);
    acc.lo.w = fmaf(a, wlo.w, acc.lo.w);
    acc.hi.x = fmaf(a, whi.x, acc.hi.x);
    acc.hi.y = fmaf(a, whi.y, acc.hi.y);
    acc.hi.z = fmaf(a, whi.z, acc.hi.z);
    acc.hi.w = fmaf(a, whi.w, acc.hi.w);
}

// ---- MFMA helpers -----------------------------------------------------------
typedef __attribute__((ext_vector_type(8)))  short    short8;  // 8 bf16
typedef __attribute__((ext_vector_type(8)))  _Float16 half8;   // 8 fp16
typedef __attribute__((ext_vector_type(16))) float    f32x16;

__device__ __forceinline__ f32x16 f16z() {
    f32x16 z;
    #pragma unroll
    for (int i = 0; i < 16; ++i) z[i] = 0.f;
    return z;
}
// hardware exp2 (single v_exp_f32)
__device__ __forceinline__ float ex2(float x) { return __builtin_amdgcn_exp2f(x); }
// fp32x2 -> packed bf16 pair via cvt builtins (KNOWN-GOOD path from R19/R20)
__device__ __forceinline__ unsigned pkb2(float a, float b) {
    __hip_bfloat16 ha = __float2bfloat16(a);
    __hip_bfloat16 hb = __float2bfloat16(b);
    return ((unsigned)*(unsigned short*)&hb << 16) | *(unsigned short*)&ha;
}
// fp32 -> bf16 (RNE), integer ops (prep-only)
__device__ __forceinline__ unsigned f2b(float f) {
    union { float f; unsigned u; } c; c.f = f;
    return (c.u + 0x7FFFu + ((c.u >> 16) & 1u)) >> 16;
}
__device__ __forceinline__ unsigned pack2(float lo, float hi) {
    return (f2b(hi) << 16) | f2b(lo);
}
// split (a,b) into packed bf16 hi words + bf16 lo residuals (prep-only)
__device__ __forceinline__ void split2(float a, float b, unsigned &hi, unsigned &lo) {
    const unsigned ha = f2b(a), hb = f2b(b);
    union { unsigned u; float f; } ua, ub; ua.u = ha << 16; ub.u = hb << 16;
    hi = (hb << 16) | ha;
    lo = pack2(a - ua.f, b - ub.f);
}
// pack two fp32 -> packed fp16 pair
__device__ __forceinline__ unsigned pkh2(float a, float b) {
    union { _Float16 h; unsigned short u; } ca, cb;
    ca.h = (_Float16)a; cb.h = (_Float16)b;
    return ((unsigned)cb.u << 16) | ca.u;
}

// ---------------- prep: weights -> fp16 single plane, co-major ---------------
__global__ __launch_bounds__(256)
void k_prep_w(const float* __restrict__ w5a, const float* __restrict__ w5c,
              const float* __restrict__ w51, const float* __restrict__ w52,
              char* __restrict__ wt1F, char* __restrict__ wt2aF, char* __restrict__ wt2bF)
{
    int idx = blockIdx.x * 256 + threadIdx.x;
    if (idx < 589824) {                       // 32*9*256*8 pairs
        const int jp = idx & 7, co = (idx >> 3) & 255, ct = idx >> 11; // ct=c*9+tap
        const int tap = ct % 9, c = ct / 9;
        const float* src = (co < 128) ? w5a : w5c;
        const int coc = co & 127;
        const int ci = c*16 + jp*2;
        const float a = src[((size_t)tap*CIN + ci)*CI + coc];
        const float b = src[((size_t)tap*CIN + ci + 1)*CI + coc];
        const int L = co*32 + jp*4;
        *(unsigned*)(wt1F + (size_t)ct*8192 + L) = pkh2(a, b);
    } else {
        int k = idx - 589824;                 // 2 * 8*9*128*8 pairs
        if (k >= 147456) return;
        const float* src = (k < 73728) ? w51 : w52;
        char* dstF = (k < 73728) ? wt2aF : wt2bF;
        if (k >= 73728) k -= 73728;
        const int jp = k & 7, co = (k >> 3) & 127, ct = k >> 10; // ct=c*9+tap
        const int tap = ct % 9, c = ct / 9;
        const int ci = c*16 + jp*2;
        const float a = src[((size_t)tap*CI + ci)*CI + co];
        const float b = src[((size_t)tap*CI + ci + 1)*CI + co];
        const int L = co*32 + jp*4;
        *(unsigned*)(dstF + (size_t)ct*4096 + L) = pkh2(a, b);
    }
}

// ---------------- prep: BN -> folded scale/bias tables -----------------------
__global__ __launch_bounds__(256)
void k_prep_bn(const float* g1, const float* b1, const float* m1, const float* v1,
               const float* g2, const float* b2, const float* m2, const float* v2,
               const float* g3, const float* b3, const float* m3, const float* v3,
               const float* g4, const float* b4, const float* m4, const float* v4,
               float* bnAs, float* bnAb, float* bnBs, float* bnBb)
{
    const int t = threadIdx.x, c = t & 127;
    {
        const float *g = (t < 128) ? g1 : g2, *b = (t < 128) ? b1 : b2;
        const float *m = (t < 128) ? m1 : m2, *v = (t < 128) ? v1 : v2;
        const float s = g[c] * rsqrtf(v[c] + BN_EPS);
        bnAs[t] = s; bnAb[t] = b[c] - m[c]*s;
    }
    {
        const float *g = (t < 128) ? g3 : g4, *b = (t < 128) ? b3 : b4;
        const float *m = (t < 128) ? m3 : m4, *v = (t < 128) ? v3 : v4;
        const float s = g[c] * rsqrtf(v[c] + BN_EPS);
        bnBs[t] = s; bnBb[t] = b[c] - m[c]*s;
    }
}

// ------- prep: x -> fp16 halo'd conv layout [row][32 chunk][66 slot][16 ch] --
__global__ __launch_bounds__(256)
void k_prep_x(const float* __restrict__ x, _Float16* __restrict__ xcv)
{
    __shared__ float Xl[16*520];
    const int t = threadIdx.x;
    const int pb = blockIdx.x * 16;           // 1024 blocks; 16 px of one row
    #pragma unroll
    for (int i = 0; i < 8; ++i) {
        const int u = t + i*256;
        const int px = u >> 7, c4 = (u & 127) * 4;
        *(float4*)&Xl[px*520 + c4] = *(const float4*)&x[(size_t)(pb + px)*CIN + c4];
    }
    __syncthreads();
    const int rowg = pb >> 6, pixb = pb & 63;
    #pragma unroll
    for (int i = 0; i < 8; ++i) {
        const int u = t + i*256;
        const int chunk = u >> 6, rem = u & 63;
        const int pl = rem >> 2, u4 = rem & 3;
        const float* src = &Xl[pl*520 + chunk*16 + u4*4];
        uint2 v;
        v.x = pkh2(src[0], src[1]);
        v.y = pkh2(src[2], src[3]);
        *(uint2*)&xcv[(((size_t)rowg*32 + chunk)*XSL + (pixb + pl + 1))*16 + u4*4] = v;
    }
    // zero the halo slots (0 and 65) of every chunk page of this row
    if (pixb == 0 && t < 64) {
        const int chunk = t >> 1, sl = (t & 1) * 65;
        uint4* dst = (uint4*)&xcv[(((size_t)rowg*32 + chunk)*XSL + sl)*16];
        uint4 z; z.x = 0u; z.y = 0u; z.z = 0u; z.w = 0u;
        dst[0] = z; dst[1] = z;
    }
}

// ---- zero halo slots of saf_h/scf_h (run AFTER conv1: region aliases xcv) ---
__global__ __launch_bounds__(256)
void k_zhalo(_Float16* __restrict__ saf_h, _Float16* __restrict__ scf_h)
{
    const int idx = blockIdx.x * 256 + threadIdx.x;   // 8192 units
    if (idx >= 8192) return;
    _Float16* arr = (idx & 4096) ? scf_h : saf_h;
    const int rem = idx & 4095;
    const int row = rem >> 4, chunk = (rem >> 1) & 7, sl = (rem & 1) * 65;
    uint4* dst = (uint4*)&arr[(((size_t)row*8 + chunk)*XSL + sl)*16];
    uint4 z; z.x = 0u; z.y = 0u; z.z = 0u; z.w = 0u;
    dst[0] = z; dst[1] = z;
}

// ---------------- MFMA 3x3 conv, fp16, 4-row block, W+X LDS-staged -----------
template<int NCHNK, int NCOTOT, int WCOBASE>
__global__ __launch_bounds__(512)
void k_convr(const _Float16* __restrict__ xcv0, const _Float16* __restrict__ xcv1,
             const _Float16* __restrict__ wtF0, const _Float16* __restrict__ wtF1,
             const float* __restrict__ bnS, const float* __restrict__ bnBi,
             float* __restrict__ out0, float* __restrict__ out1)
{
    constexpr int WU4  = 1152;                // 9 taps * 128 u4 (18432 B)
    constexpr int XU4  = 792;                 // 6 pages * 132 u4 (12672 B)
    constexpr int BUFB = (WU4 + XU4) * 16;    // 31104 B per buffer
    __shared__ __align__(16) char Ls[2*BUFB];

    const int t     = threadIdx.x;
    const int wgid  = blockIdx.x;             // 256
    const int slice = wgid & 3;
    const int rg    = wgid >> 2;              // 0..63 (4-row group)
    const int sel   = slice >> 1;
    const int ch2   = slice & 1;
    const _Float16* xcv = sel ? xcv1 : xcv0;
    const _Float16* wtF = sel ? wtF1 : wtF0;
    float* dst = sel ? out1 : out0;

    const int hh0 = (rg*4) & 63;              // row-in-image of group start
    const int l = t & 63, w = t >> 6;
    const int lo5 = l & 31, hf = l >> 5;
    const int r = w >> 1, mi = w & 1;
    const int cobase0 = WCOBASE*sel + ch2*64;

    // ---- hoisted stage decode: 1944 u4 units, 4 slots/thread ----
    bool sAct[4]; bool sIsW[4]; int sDst[4]; size_t sSrc[4]; unsigned sStr[4];
    #pragma unroll
    for (int i = 0; i < 4; ++i) {
        const int u = t + i*512;
        sAct[i] = false; sIsW[i] = false; sDst[i] = -1; sSrc[i] = 0; sStr[i] = 0;
        if (u < WU4) {
            const int tap = u >> 7, rem = u & 127;
            const int co = rem >> 1, whf = rem & 1;
            sAct[i] = true; sIsW[i] = true;
            sSrc[i] = (size_t)(tap*NCOTOT + cobase0 + co)*32 + whf*16;
            sStr[i] = (unsigned)(9*NCOTOT*32);
            sDst[i] = (tap*128 + whf*64 + co) * 16;
        } else if (u < WU4 + XU4) {
            const int j = u - WU4;
            const int page = j / 132, rem132 = j - page*132;
            const int slot = rem132 >> 1, xhf = rem132 & 1;
            const int hin = hh0 + page - 1;               // row in image
            sAct[i] = (hin >= 0 && hin < Hn);
            const int gr = rg*4 + page - 1;               // global row
            sSrc[i] = (size_t)gr*NCHNK*2112 + (size_t)(slot*32 + xhf*16);
            sStr[i] = 2112u;
            sDst[i] = WU4*16 + page*2112 + ((slot*32 + xhf*16) ^ ((slot & 7) << 4));
        }
    }
    // hoisted compute X offsets (dy, dx) for this wave's (r, mi)
    int xoff[3][3];
    #pragma unroll
    for (int dy = 0; dy < 3; ++dy)
        #pragma unroll
        for (int dx = 0; dx < 3; ++dx) {
            const int s = mi*32 + lo5 + dx;
            xoff[dy][dx] = WU4*16 + (r + dy)*2112 + ((s*32 + hf*16) ^ ((s & 7) << 4));
        }

    f32x16 acc[2];
    acc[0] = f16z(); acc[1] = f16z();

    uint4 xr[4];
    auto loadS = [&](int c) {
        #pragma unroll
        for (int i = 0; i < 4; ++i) {
            uint4 v; v.x = 0u; v.y = 0u; v.z = 0u; v.w = 0u;
            if (sAct[i]) {
                const char* base = sIsW[i] ? (const char*)wtF : (const char*)xcv;
                v = *(const uint4*)(base + sSrc[i] + (size_t)c*sStr[i]);
            }
            xr[i] = v;
        }
    };

    loadS(0);
    int p = 0;
    for (int c = 0; c < NCHNK; ++c) {
        char* Lp = Ls + p*BUFB;
        #pragma unroll
        for (int i = 0; i < 4; ++i)
            if (sDst[i] >= 0) *(uint4*)(Lp + sDst[i]) = xr[i];
        __syncthreads();
        if (c + 1 < NCHNK) loadS(c + 1);
        // ---- compute: 9 taps, 2 co-tiles each ----
        #pragma unroll
        for (int dy = 0; dy < 3; ++dy)
            #pragma unroll
            for (int dx = 0; dx < 3; ++dx) {
                const half8 xf = *(const half8*)(Lp + xoff[dy][dx]);
                const half8 w0 = *(const half8*)(Lp + ((dy*3 + dx)*128 + hf*64 + lo5)*16);
                const half8 w1 = *(const half8*)(Lp + ((dy*3 + dx)*128 + hf*64 + 32 + lo5)*16);
                acc[0] = __builtin_amdgcn_mfma_f32_32x32x16_f16(w0, xf, acc[0], 0, 0, 0);
                acc[1] = __builtin_amdgcn_mfma_f32_32x32x16_f16(w1, xf, acc[1], 0, 0, 0);
            }
        p ^= 1;
    }
    // ---- epilogue: folded BN + ReLU (fp32 out) ----
    const int px = mi*32 + lo5;
    const size_t pg = (size_t)(rg*4 + r)*Wn + px;
    #pragma unroll
    for (int cot = 0; cot < 2; ++cot)
        #pragma unroll
        for (int rr = 0; rr < 16; ++rr) {
            const int crow = (rr & 3) + 8*(rr >> 2) + 4*hf;
            const int och = ch2*64 + cot*32 + crow;
            const int bnidx = sel*128 + och;
            dst[pg*CI + och] = fmaxf(fmaf(acc[cot][rr], bnS[bnidx], bnBi[bnidx]), 0.f);
        }
}

// ---------------- K2a: q,k 1x1 conv -> bf16 (q pre-scaled by log2e) ----------
__global__ __launch_bounds__(256)
void k_qk(const float* __restrict__ feat1,
          const float* __restrict__ wq, const float* __restrict__ bq,
          const float* __restrict__ wk, const float* __restrict__ bk,
          __hip_bfloat16* __restrict__ qb, __hip_bfloat16* __restrict__ kb)
{
    __shared__ float Al[64*129];
    __shared__ __align__(16) float Wl[128*32];
    const int t = threadIdx.x;
    const int pb = blockIdx.x * 64;
    for (int idx = t; idx < 64*128; idx += 256) {
        const int p = idx >> 7, ci = idx & 127;
        Al[p*129 + ci] = feat1[(size_t)(pb + p)*CI + ci];
    }
    for (int idx = t; idx < 128*32; idx += 256) {
        const int ci = idx >> 5, c = idx & 31;
        Wl[idx] = (c < 16) ? wq[ci*16 + c] : wk[ci*16 + (c - 16)];
    }
    __syncthreads();
    const int p = t & 63, cg = t >> 6, co = cg * 8;
    F8 acc = f8zero();
    #pragma unroll 8
    for (int ci = 0; ci < 128; ++ci) {
        const float a = Al[p*129 + ci];
        const float4 wlo = *(const float4*)&Wl[ci*32 + co];
        const float4 whi = *(const float4*)&Wl[ci*32 + co + 4];
        fma8(acc, a, wlo, whi);
    }
    const float* af = (const float*)&acc;
    #pragma unroll
    for (int j = 0; j < 8; ++j) {
        const int c = co + j;
        if (c < 16) qb[(size_t)(pb + p)*16 + c]        = __float2bfloat16((af[j] + bq[c]) * LOG2E);
        else        kb[(size_t)(pb + p)*16 + (c - 16)] = __float2bfloat16(af[j] + bk[c - 16]);
    }
}

// ---------------- K2b: v 1x1 conv -> bf16 COALESCED [b][key/16][c][16key] ----
__global__ __launch_bounds__(256)
void k_v(const float* __restrict__ feat1, const float* __restrict__ wv,
         const float* __restrict__ bv, __hip_bfloat16* __restrict__ vbT)
{
    __shared__ float Al[32*129];
    __shared__ __align__(16) float Wl[64*128];
    const int t = threadIdx.x;
    const int pb = blockIdx.x * 32;
    for (int idx = t; idx < 32*128; idx += 256) {
        const int p = idx >> 7, ci = idx & 127;
        Al[p*129 + ci] = feat1[(size_t)(pb + p)*CI + ci];
    }
    const int px = t & 15, co = (t >> 4) * 8;
    F8 acc0 = f8zero(), acc1 = f8zero();
    for (int ch = 0; ch < 2; ++ch) {
        __syncthreads();
        #pragma unroll
        for (int r = 0; r < 8; ++r) {
            const int i4 = t + r*256;
            const int kk = i4 >> 5, c4 = (i4 & 31) * 4;
            *(float4*)&Wl[kk*128 + c4] = *(const float4*)&wv[(size_t)(ch*64 + kk)*CI + c4];
        }
        __syncthreads();
        #pragma unroll 4
        for (int kk = 0; kk < 64; ++kk) {
            const float a0 = Al[px*129 + ch*64 + kk];
            const float a1 = Al[(px+16)*129 + ch*64 + kk];
            const float4 wlo = *(const float4*)&Wl[kk*128 + co];
            const float4 whi = *(const float4*)&Wl[kk*128 + co + 4];
            fma8(acc0, a0, wlo, whi);
            fma8(acc1, a1, wlo, whi);
        }
    }
    const int p0 = pb + px;
    const int bb = p0 / HWn, pin0 = p0 % HWn;
    const int k16a = pin0 >> 4, ko = pin0 & 15;
    const float* a0f = (const float*)&acc0;
    const float* a1f = (const float*)&acc1;
    #pragma unroll
    for (int j = 0; j < 8; ++j) {
        const int c = co + j;
        const size_t base = ((size_t)bb*256*CI*16) + (size_t)c*16 + ko;
        vbT[base + (size_t)k16a*CI*16]       = __float2bfloat16(a0f[j] + bv[c]);
        vbT[base + (size_t)(k16a + 1)*CI*16] = __float2bfloat16(a1f[j] + bv[c]);
    }
}

// ---------------- K3: PAM flash attention, 4-wave K-split --------------------
// hw exp2 (v_exp_f32) + pointer-increment K/V addressing kept from R21;
// P packing reverted to header-cvt pkb2 (bisect: R21's v_cvt_pk asm suspect).
__global__ __launch_bounds__(256)
void k_pam(const __hip_bfloat16* __restrict__ qb, const __hip_bfloat16* __restrict__ kb,
           const __hip_bfloat16* __restrict__ vbT, const float* __restrict__ feat1,
           const float* __restrict__ gamma, _Float16* __restrict__ saf_h)
{
    __shared__ __align__(16) char pbuf[16896];   // Ppk[4][1024 u32] -> osum[32][132] f32
    __shared__ float msArr[4][32];
    __shared__ float ssArr[4][32];
    __shared__ float ssum[32];
    const int t  = threadIdx.x;
    const int wv = t >> 6, l = t & 63;
    const int lo5 = l & 31, h = l >> 5;
    unsigned* Ppk = (unsigned*)(pbuf + wv*4096);
    float* osum = (float*)pbuf;

    // batch-pinned XCD decode (512 blocks: 128 per batch on 2 XCDs)
    const int wgid = blockIdx.x;
    const int xcd  = wgid & 7;
    const int bb   = xcd >> 1;                       // batch
    const int qt   = ((wgid >> 3) << 1) | (xcd & 1); // q-tile 0..127
    const int q0   = bb*HWn + qt*32;                 // global pixel row base
    const size_t jb = (size_t)bb * HWn;

    const short8 qfrag = *(const short8*)&qb[(size_t)(q0 + lo5)*16 + 8*h];
    const f32x16 zro = f16z();

    f32x16 o[4];
    #pragma unroll
    for (int cb = 0; cb < 4; ++cb) o[cb] = f16z();

    float m_run = -1e30f, s_run = 0.f;

    const int kbeg = wv*1024, kend = kbeg + 1024;
    // lane-base byte pointers, advanced by constant strides per tile
    const char* kp = (const char*)kb + (size_t)(jb + kbeg + lo5)*32 + 16*h;
    const char* vp = (const char*)vbT + (size_t)bb*256*CI*32
                     + ((size_t)(kbeg >> 4)*CI + lo5)*32 + 16*h;
    short8 kf0 = *(const short8*)kp;
    short8 kf1 = *(const short8*)(kp + 1024);
    kp += 2048;

    for (int k0 = kbeg; k0 < kend; k0 += 64) {
        short8 vf[4][4];
        #pragma unroll
        for (int s = 0; s < 4; ++s)
            #pragma unroll
            for (int cb = 0; cb < 4; ++cb)
                vf[s][cb] = *(const short8*)(vp + s*4096 + cb*1024);
        vp += 16384;

        f32x16 e0 = __builtin_amdgcn_mfma_f32_32x32x16_bf16(kf0, qfrag, zro, 0, 0, 0);
        f32x16 e1 = __builtin_amdgcn_mfma_f32_32x32x16_bf16(kf1, qfrag, zro, 0, 0, 0);

        // prefetch next tile's K fragments (breaks load->QK serial chain)
        if (k0 + 64 < kend) {
            kf0 = *(const short8*)kp;
            kf1 = *(const short8*)(kp + 1024);
            kp += 2048;
        }

        // tree max (depth ~5)
        float mx8[8];
        #pragma unroll
        for (int r = 0; r < 8; ++r)
            mx8[r] = fmaxf(fmaxf(e0[r], e0[r+8]), fmaxf(e1[r], e1[r+8]));
        mx8[0] = fmaxf(mx8[0], mx8[4]);
        mx8[1] = fmaxf(mx8[1], mx8[5]);
        mx8[2] = fmaxf(mx8[2], mx8[6]);
        mx8[3] = fmaxf(mx8[3], mx8[7]);
        mx8[0] = fmaxf(mx8[0], mx8[2]);
        mx8[1] = fmaxf(mx8[1], mx8[3]);
        float mt = fmaxf(mx8[0], mx8[1]);
        mt = fmaxf(mt, __shfl_xor(mt, 32));

        if (__any(mt > m_run + 11.5416f)) {   // 8 * log2(e)
            const float mnew = fmaxf(m_run, mt);
            const float sc = ex2(m_run - mnew);
            s_run *= sc;
            #pragma unroll
            for (int cb = 0; cb < 4; ++cb)
                #pragma unroll
                for (int r = 0; r < 16; ++r) o[cb][r] *= sc;
            m_run = mnew;
        }

        #pragma unroll
        for (int r = 0; r < 16; ++r) {
            e0[r] = ex2(e0[r] - m_run);
            e1[r] = ex2(e1[r] - m_run);
        }
        // tree sum (depth ~5)
        {
            float s8[8];
            #pragma unroll
            for (int r = 0; r < 8; ++r)
                s8[r] = (e0[r] + e0[r+8]) + (e1[r] + e1[r+8]);
            s8[0] += s8[4]; s8[1] += s8[5]; s8[2] += s8[6]; s8[3] += s8[7];
            s8[0] += s8[2]; s8[1] += s8[3];
            s_run += s8[0] + s8[1];
        }

        #pragma unroll
        for (int r = 0; r < 16; r += 2) {
            const int pidx = ((r & 3) >> 1) + 4*(r >> 2) + 2*h;
            Ppk[pidx*32 + lo5]        = pkb2(e0[r], e0[r+1]);
            Ppk[(16 + pidx)*32 + lo5] = pkb2(e1[r], e1[r+1]);
        }
        #pragma unroll
        for (int s = 0; s < 4; ++s) {
            union { unsigned u[4]; short8 s8; } P;
            #pragma unroll
            for (int w = 0; w < 4; ++w)
                P.u[w] = Ppk[(s*8 + 4*h + w)*32 + lo5];
            #pragma unroll
            for (int cb = 0; cb < 4; ++cb)
                o[cb] = __builtin_amdgcn_mfma_f32_32x32x16_bf16(vf[s][cb], P.s8, o[cb], 0, 0, 0);
        }
    }

    // ---- publish per-wave (m, s) ----
    const float s_w = s_run + __shfl_xor(s_run, 32);
    if (h == 0) { msArr[wv][lo5] = m_run; ssArr[wv][lo5] = s_w; }
    __syncthreads();                          // all waves done with Ppk too

    // ---- merge ----
    float M = msArr[0][lo5];
    #pragma unroll
    for (int w = 1; w < 4; ++w) M = fmaxf(M, msArr[w][lo5]);
    float stot = 0.f;
    #pragma unroll
    for (int w = 0; w < 4; ++w) stot += ex2(msArr[w][lo5] - M) * ssArr[w][lo5];
    if (wv == 0 && h == 0) ssum[lo5] = stot;
    const float myscale = ex2(m_run - M);
    #pragma unroll
    for (int cb = 0; cb < 4; ++cb)
        #pragma unroll
        for (int r = 0; r < 16; ++r) o[cb][r] *= myscale;

    for (int w = 0; w < 4; ++w) {
        if (wv == w) {
            #pragma unroll
            for (int cb = 0; cb < 4; ++cb)
                #pragma unroll
                for (int r = 0; r < 16; ++r) {
                    const int c = cb*32 + (r & 3) + 8*(r >> 2) + 4*h;
                    float* p = &osum[lo5*132 + c];
                    if (w == 0) *p = o[cb][r]; else *p += o[cb][r];
                }
        }
        __syncthreads();
    }

    // ---- normalize + residual, write fp16 halo'd conv layout ----
    const float g = gamma[0];
    const int qloc = t >> 3, ch8 = t & 7;
    const float inv = 1.f / ssum[qloc];
    const int pgl = q0 + qloc;
    const int rowp = pgl >> 6, pixp = pgl & 63;
    const size_t gbase = (size_t)pgl*CI + ch8*16;
    union { _Float16 hv[16]; uint4 u[2]; } tmp;
    #pragma unroll
    for (int j = 0; j < 16; ++j)
        tmp.hv[j] = (_Float16)(g*(osum[qloc*132 + ch8*16 + j]*inv) + feat1[gbase + j]);
    uint4* dsth = (uint4*)&saf_h[(((size_t)rowp*8 + ch8)*XSL + (pixp + 1))*16];
    dsth[0] = tmp.u[0];
    dsth[1] = tmp.u[1];
}

// ---------------- K4x: transpose feat2 -> bf16 hi/lo [b][c][HW] --------------
__global__ __launch_bounds__(256)
void k_xpose(const float* __restrict__ feat2,
             char* __restrict__ f2TH, char* __restrict__ f2TL)
{
    __shared__ float Xl[64*129];
    const int t = threadIdx.x;
    const int pb = blockIdx.x * 64;
    const int bb = pb / HWn, pin = pb % HWn;
    for (int idx = t; idx < 64*128; idx += 256) {
        const int p = idx >> 7, ci = idx & 127;
        Xl[p*129 + ci] = feat2[(size_t)(pb + p)*CI + ci];
    }
    __syncthreads();
    const int c = t >> 1, half = t & 1;
    const size_t rowb = ((size_t)(bb*CI + c)*HWn + pin + half*32) * 2;
    #pragma unroll
    for (int j = 0; j < 16; ++j) {
        const float a = Xl[(half*32 + 2*j)*129 + c];
        const float b = Xl[(half*32 + 2*j + 1)*129 + c];
        unsigned hi, lo; split2(a, b, hi, lo);
        *(unsigned*)(f2TH + rowb + 4*j) = hi;
        *(unsigned*)(f2TL + rowb + 4*j) = lo;
    }
}

// ---------------- K4a: CAM energy via MFMA, split-K partials -----------------
__global__ __launch_bounds__(256)
void k_cam_energy_m(const char* __restrict__ f2TH, const char* __restrict__ f2TL,
                    float* __restrict__ epart)
{
    __shared__ __align__(16) char Vh[128*256];
    __shared__ __align__(16) char Vl[128*256];
    const int t = threadIdx.x;
    const int ks = blockIdx.x, bb = blockIdx.y;
    const int l = t & 63, w = t >> 6;
    const int lo5 = l & 31, hf = l >> 5;

    #pragma unroll
    for (int pass = 0; pass < 8; ++pass) {
        const int slot = pass*256 + t;
        const int c = slot >> 4, g = slot & 15;
        const size_t gaddr = ((size_t)(bb*CI + c)*HWn + ks*128)*2 + g*16;
        const int laddr = c*256 + ((g*16) ^ ((c & 15) << 4));
        *(float4*)(Vh + laddr) = *(const float4*)(f2TH + gaddr);
        *(float4*)(Vl + laddr) = *(const float4*)(f2TL + gaddr);
    }
    __syncthreads();

    f32x16 acc[4];
    #pragma unroll
    for (int nj = 0; nj < 4; ++nj) acc[nj] = f16z();
    const int cA = w*32 + lo5;
    const int swA = (cA & 15) << 4;

    #pragma unroll
    for (int kk = 0; kk < 8; ++kk) {
        const int kb = kk*32 + hf*16;
        const short8 ah = *(const short8*)(Vh + cA*256 + (kb ^ swA));
        const short8 al = *(const short8*)(Vl + cA*256 + (kb ^ swA));
        #pragma unroll
        for (int nj = 0; nj < 4; ++nj) {
            const int dB = nj*32 + lo5;
            const int swB = (dB & 15) << 4;
            const short8 bh = *(const short8*)(Vh + dB*256 + (kb ^ swB));
            const short8 bl = *(const short8*)(Vl + dB*256 + (kb ^ swB));
            acc[nj] = __builtin_amdgcn_mfma_f32_32x32x16_bf16(ah, bh, acc[nj], 0, 0, 0);
            acc[nj] = __builtin_amdgcn_mfma_f32_32x32x16_bf16(al, bh, acc[nj], 0, 0, 0);
            acc[nj] = __builtin_amdgcn_mfma_f32_32x32x16_bf16(ah, bl, acc[nj], 0, 0, 0);
        }
    }
    float* ep = epart + ((size_t)(bb*32 + ks)*CI)*CI;
    #pragma unroll
    for (int nj = 0; nj < 4; ++nj)
        #pragma unroll
        for (int r = 0; r < 16; ++r) {
            const int c = w*32 + (r & 3) + 8*(r >> 2) + 4*hf;
            ep[(size_t)c*CI + nj*32 + lo5] = acc[nj][r];
        }
}

// ---------------- K4b: fused reduce + max-subtract softmax -------------------
__global__ __launch_bounds__(64)
void k_cam_rs(const float* __restrict__ epart, float* __restrict__ att)
{
    const int lane = threadIdx.x;
    const int row = blockIdx.x;             // b*128 + c
    const int bb = row >> 7, c = row & 127;
    float2 e = make_float2(0.f, 0.f);
    for (int ks = 0; ks < 32; ++ks) {
        const float2 v = *(const float2*)&epart[
            ((size_t)(bb*32 + ks)*CI + c)*CI + lane*2];
        e.x += v.x; e.y += v.y;
    }
    float M = fmaxf(e.x, e.y);
    #pragma unroll
    for (int off = 32; off > 0; off >>= 1) M = fmaxf(M, __shfl_xor(M, off));
    const float en0 = M - e.x, en1 = M - e.y;
    float mx = fmaxf(en0, en1);
    #pragma unroll
    for (int off = 32; off > 0; off >>= 1) mx = fmaxf(mx, __shfl_xor(mx, off));
    const float p0 = __expf(en0 - mx), p1 = __expf(en1 - mx);
    float s = p0 + p1;
    #pragma unroll
    for (int off = 32; off > 0; off >>= 1) s += __shfl_xor(s, off);
    const float inv = 1.f / s;
    float2 o; o.x = p0*inv; o.y = p1*inv;
    *(float2*)&att[(size_t)row*CI + lane*2] = o;
}

// ---------------- K4c: CAM apply -> fp16 halo'd conv layout ------------------
__global__ __launch_bounds__(256)
void k_cam_apply(const float* __restrict__ feat2, const float* __restrict__ att,
                 const float* __restrict__ gamma, _Float16* __restrict__ scf_h)
{
    __shared__ float Xl[64*129];
    __shared__ __align__(16) float aT[128*64];
    const int t = threadIdx.x;
    const int pb = blockIdx.x * 64;
    const int bb = pb / HWn;
    const int ch = blockIdx.y * 64;
    for (int idx = t; idx < 64*128; idx += 256) {
        const int p = idx >> 7, ci = idx & 127;
        Xl[p*129 + ci] = feat2[(size_t)(pb + p)*CI + ci];
    }
    for (int idx = t; idx < 128*64; idx += 256) {
        const int d = idx >> 6, cc = idx & 63;
        aT[d*64 + cc] = att[((size_t)bb*CI + ch + cc)*CI + d];
    }
    __syncthreads();
    const int px = t & 63, cg = t >> 6;
    F8 accA = f8zero(), accB = f8zero();
    #pragma unroll 4
    for (int d = 0; d < 128; ++d) {
        const float xv = Xl[px*129 + d];
        const float* ap = &aT[d*64 + cg*16];
        const float4 a0 = *(const float4*)&ap[0];
        const float4 a1 = *(const float4*)&ap[4];
        const float4 a2 = *(const float4*)&ap[8];
        const float4 a3 = *(const float4*)&ap[12];
        fma8(accA, xv, a0, a1);
        fma8(accB, xv, a2, a3);
    }
    const float g = gamma[0];
    const float* fa = (const float*)&accA;
    const float* fb = (const float*)&accB;
    const int p0g = pb + px;
    const int rowA = p0g >> 6, pixA = p0g & 63;
    const int chunkA = (ch >> 4) + cg;
    const size_t baseA = (((size_t)rowA*8 + chunkA)*XSL + (pixA + 1))*16;
    #pragma unroll
    for (int j = 0; j < 8; ++j) {
        const int cA = ch + cg*16 + j;
        const int cB = cA + 8;
        scf_h[baseA + j]     = (_Float16)(g*fa[j] + Xl[px*129 + cA]);
        scf_h[baseA + 8 + j] = (_Float16)(g*fb[j] + Xl[px*129 + cB]);
    }
}

// ---------------- K7: final 1x1 conv (sum of two branches) -> out ------------
__global__ __launch_bounds__(256)
void k_final(const float* __restrict__ sa, const float* __restrict__ sc,
             const float* __restrict__ w8, float* __restrict__ out)
{
    __shared__ float Xl[64*129];
    __shared__ float w8l[128*COn];
    const int t = threadIdx.x;
    const int pb = blockIdx.x * 64;
    for (int idx = t; idx < 64*128; idx += 256) {
        const int p = idx >> 7, ci = idx & 127;
        const size_t gi = (size_t)(pb + p)*CI + ci;
        Xl[p*129 + ci] = sa[gi] + sc[gi];
    }
    for (int idx = t; idx < 128*COn; idx += 256) w8l[idx] = w8[idx];
    __syncthreads();
    for (int idx = t; idx < 64*COn; idx += 256) {
        const int p = idx / COn, co = idx - p*COn;
        float acc = 0.f;
        #pragma unroll 8
        for (int ci = 0; ci < 128; ++ci)
            acc = fmaf(Xl[p*129 + ci], w8l[ci*COn + co], acc);
        out[(size_t)(pb + p)*COn + co] = acc;
    }
}

extern "C" void kernel_launch(void* const* d_in, const int* in_sizes, int n_in,
                              void* d_out, int out_size, void* d_ws, size_t ws_size,
                              hipStream_t stream)
{
    const float* x    = (const float*)d_in[0];
    const float* w5a  = (const float*)d_in[1];
    const float* w5c  = (const float*)d_in[2];
    const float* wq   = (const float*)d_in[3];
    const float* bq   = (const float*)d_in[4];
    const float* wk   = (const float*)d_in[5];
    const float* bk   = (const float*)d_in[6];
    const float* wv   = (const float*)d_in[7];
    const float* bv   = (const float*)d_in[8];
    const float* pgam = (const float*)d_in[9];
    const float* cgam = (const float*)d_in[10];
    const float* w51  = (const float*)d_in[11];
    const float* w52  = (const float*)d_in[12];
    const float* w8   = (const float*)d_in[13];
    const float* bn1g = (const float*)d_in[14];
    const float* bn1b = (const float*)d_in[15];
    const float* bn1m = (const float*)d_in[16];
    const float* bn1v = (const float*)d_in[17];
    const float* bn2g = (const float*)d_in[18];
    const float* bn2b = (const float*)d_in[19];
    const float* bn2m = (const float*)d_in[20];
    const float* bn2v = (const float*)d_in[21];
    const float* bn3g = (const float*)d_in[22];
    const float* bn3b = (const float*)d_in[23];
    const float* bn3m = (const float*)d_in[24];
    const float* bn3v = (const float*)d_in[25];
    const float* bn4g = (const float*)d_in[26];
    const float* bn4b = (const float*)d_in[27];
    const float* bn4m = (const float*)d_in[28];
    const float* bn4v = (const float*)d_in[29];

    char* wsb = (char*)d_ws;
    float* feat1 = (float*)(wsb + 0);
    char*  f2TH  = wsb + 0;                     // 4 MB
    char*  f2TL  = wsb + 4194304;               // 4 MB
    float* feat2 = (float*)(wsb + 8388608);
    _Float16* xcv   = (_Float16*)(wsb + 16777216);   // 17,301,504 B
    _Float16* saf_h = (_Float16*)(wsb + 16777216);   // 4,325,376 B (post-conv1)
    _Float16* scf_h = (_Float16*)(wsb + 21102592);   // 4,325,376 B -> 25427968
    float*    epart = (float*)(wsb + 25427968);      // 8 MB -> 33816576
    float* att = (float*)(wsb + 33816576);           // 256 KB -> 34078720
    __hip_bfloat16* qb16 = (__hip_bfloat16*)(wsb + 34078720);  // 512 KB
    __hip_bfloat16* kb16 = (__hip_bfloat16*)(wsb + 34603008);  // 512 KB
    __hip_bfloat16* vbT  = (__hip_bfloat16*)(wsb + 35127296);  // 4 MB -> 39321600
    char* wt1F  = wsb + 39321600;               // 2359296 -> 41680896
    char* wt2aF = wsb + 41680896;               // 294912  -> 41975808
    char* wt2bF = wsb + 41975808;               // 294912  -> 42270720
    float* bnAs = (float*)(wsb + 42270720);
    float* bnAb = (float*)(wsb + 42271744);
    float* bnBs = (float*)(wsb + 42272768);
    float* bnBb = (float*)(wsb + 42273792);     // high-water 42274816
    float* sa_conv = feat1;
    float* sc_conv = feat2;
    float* out  = (float*)d_out;

    k_prep_w<<<dim3(2880), 256, 0, stream>>>(w5a, w5c, w51, w52, wt1F, wt2aF, wt2bF);
    k_prep_bn<<<dim3(1), 256, 0, stream>>>(bn1g, bn1b, bn1m, bn1v, bn2g, bn2b, bn2m, bn2v,
                                           bn3g, bn3b, bn3m, bn3v, bn4g, bn4b, bn4m, bn4v,
                                           bnAs, bnAb, bnBs, bnBb);
    k_prep_x<<<dim3(1024), 256, 0, stream>>>(x, xcv);
    k_convr<32, 256, 128><<<dim3(256), 512, 0, stream>>>(
        xcv, xcv, (const _Float16*)wt1F, (const _Float16*)wt1F, bnAs, bnAb, feat1, feat2);
    k_zhalo<<<dim3(32), 256, 0, stream>>>(saf_h, scf_h);   // after conv1: aliases xcv
    k_qk<<<dim3(NPIX/64), 256, 0, stream>>>(feat1, wq, bq, wk, bk, qb16, kb16);
    k_v<<<dim3(NPIX/32), 256, 0, stream>>>(feat1, wv, bv, vbT);
    k_pam<<<dim3(NPIX/32), 256, 0, stream>>>(qb16, kb16, vbT, feat1, pgam, saf_h);
    k_xpose<<<dim3(NPIX/64), 256, 0, stream>>>(feat2, f2TH, f2TL);
    k_cam_energy_m<<<dim3(32, Bn), 256, 0, stream>>>(f2TH, f2TL, epart);
    k_cam_rs<<<dim3(Bn*CI), 64, 0, stream>>>(epart, att);
    k_cam_apply<<<dim3(NPIX/64, 2), 256, 0, stream>>>(feat2, att, cgam, scf_h);
    k_convr<8, 128, 0><<<dim3(256), 512, 0, stream>>>(
        saf_h, scf_h, (const _Float16*)wt2aF, (const _Float16*)wt2bF,
        bnBs, bnBb, sa_conv, sc_conv);
    k_final<<<dim3(NPIX/64), 256, 0, stream>>>(sa_conv, sc_conv, w8, out);
}

// Round 23
// 206.268 us; speedup vs baseline: 1.1248x; 1.0127x over previous
//
#include <hip/hip_runtime.h>
#include <hip/hip_bf16.h>
#include <math.h>

#define BN_EPS 1e-3f
#define LOG2E 1.44269504088896f

constexpr int Bn = 4, Hn = 64, Wn = 64, CIN = 512, CI = 128;
constexpr int HWn = Hn * Wn;        // 4096
constexpr int NPIX = Bn * HWn;      // 16384
constexpr int COn = 19;
constexpr int XSL = 66;             // conv page slots (64 px + 2 halo)
constexpr int XPG = XSL * 16;       // 1056 elements per (row,chunk) page

struct F8 { float4 lo, hi; };

__device__ __forceinline__ F8 f8zero() {
    F8 r; r.lo = make_float4(0.f,0.f,0.f,0.f); r.hi = make_float4(0.f,0.f,0.f,0.f); return r;
}
__device__ __forceinline__ void fma8(F8 &acc, float a, const float4 &wlo, const float4 &whi) {
    acc.lo.x = fmaf(a, wlo.x, acc.lo.x);
    acc.lo.y = fmaf(a, wlo.y, acc.lo.y);
    acc.lo.z = fmaf(a, wlo.z, acc.lo.z);
    acc.lo.w = fmaf(a, wlo.w, acc.lo.w);
    acc.hi.x = fmaf(a, whi.x, acc.hi.x);
    acc.hi.y = fmaf(a, whi.y, acc.hi.y);
    acc.hi.z = fmaf(a, whi.z, acc.hi.z);
    acc.hi.w = fmaf(a, whi.w, acc.hi.w);
}

// ---- MFMA helpers -----------------------------------------------------------
typedef __attribute__((ext_vector_type(8)))  short    short8;  // 8 bf16
typedef __attribute__((ext_vector_type(8)))  _Float16 half8;   // 8 fp16
typedef __attribute__((ext_vector_type(16))) float    f32x16;

__device__ __forceinline__ f32x16 f16z() {
    f32x16 z;
    #pragma unroll
    for (int i = 0; i < 16; ++i) z[i] = 0.f;
    return z;
}
// hardware exp2 (single v_exp_f32)
__device__ __forceinline__ float ex2(float x) { return __builtin_amdgcn_exp2f(x); }
// fp32x2 -> packed bf16 pair via cvt builtins (known-good)
__device__ __forceinline__ unsigned pkb2(float a, float b) {
    __hip_bfloat16 ha = __float2bfloat16(a);
    __hip_bfloat16 hb = __float2bfloat16(b);
    return ((unsigned)*(unsigned short*)&hb << 16) | *(unsigned short*)&ha;
}
// fp32 -> bf16 (RNE), integer ops (prep-only)
__device__ __forceinline__ unsigned f2b(float f) {
    union { float f; unsigned u; } c; c.f = f;
    return (c.u + 0x7FFFu + ((c.u >> 16) & 1u)) >> 16;
}
__device__ __forceinline__ unsigned pack2(float lo, float hi) {
    return (f2b(hi) << 16) | f2b(lo);
}
// split (a,b) into packed bf16 hi words + bf16 lo residuals (prep-only)
__device__ __forceinline__ void split2(float a, float b, unsigned &hi, unsigned &lo) {
    const unsigned ha = f2b(a), hb = f2b(b);
    union { unsigned u; float f; } ua, ub; ua.u = ha << 16; ub.u = hb << 16;
    hi = (hb << 16) | ha;
    lo = pack2(a - ua.f, b - ub.f);
}
// pack two fp32 -> packed fp16 pair
__device__ __forceinline__ unsigned pkh2(float a, float b) {
    union { _Float16 h; unsigned short u; } ca, cb;
    ca.h = (_Float16)a; cb.h = (_Float16)b;
    return ((unsigned)cb.u << 16) | ca.u;
}

// ---------------- prep: weights -> fp16 single plane, co-major ---------------
__global__ __launch_bounds__(256)
void k_prep_w(const float* __restrict__ w5a, const float* __restrict__ w5c,
              const float* __restrict__ w51, const float* __restrict__ w52,
              char* __restrict__ wt1F, char* __restrict__ wt2aF, char* __restrict__ wt2bF)
{
    int idx = blockIdx.x * 256 + threadIdx.x;
    if (idx < 589824) {                       // 32*9*256*8 pairs
        const int jp = idx & 7, co = (idx >> 3) & 255, ct = idx >> 11; // ct=c*9+tap
        const int tap = ct % 9, c = ct / 9;
        const float* src = (co < 128) ? w5a : w5c;
        const int coc = co & 127;
        const int ci = c*16 + jp*2;
        const float a = src[((size_t)tap*CIN + ci)*CI + coc];
        const float b = src[((size_t)tap*CIN + ci + 1)*CI + coc];
        const int L = co*32 + jp*4;
        *(unsigned*)(wt1F + (size_t)ct*8192 + L) = pkh2(a, b);
    } else {
        int k = idx - 589824;                 // 2 * 8*9*128*8 pairs
        if (k >= 147456) return;
        const float* src = (k < 73728) ? w51 : w52;
        char* dstF = (k < 73728) ? wt2aF : wt2bF;
        if (k >= 73728) k -= 73728;
        const int jp = k & 7, co = (k >> 3) & 127, ct = k >> 10; // ct=c*9+tap
        const int tap = ct % 9, c = ct / 9;
        const int ci = c*16 + jp*2;
        const float a = src[((size_t)tap*CI + ci)*CI + co];
        const float b = src[((size_t)tap*CI + ci + 1)*CI + co];
        const int L = co*32 + jp*4;
        *(unsigned*)(dstF + (size_t)ct*4096 + L) = pkh2(a, b);
    }
}

// ---------------- prep: BN -> folded scale/bias tables -----------------------
__global__ __launch_bounds__(256)
void k_prep_bn(const float* g1, const float* b1, const float* m1, const float* v1,
               const float* g2, const float* b2, const float* m2, const float* v2,
               const float* g3, const float* b3, const float* m3, const float* v3,
               const float* g4, const float* b4, const float* m4, const float* v4,
               float* bnAs, float* bnAb, float* bnBs, float* bnBb)
{
    const int t = threadIdx.x, c = t & 127;
    {
        const float *g = (t < 128) ? g1 : g2, *b = (t < 128) ? b1 : b2;
        const float *m = (t < 128) ? m1 : m2, *v = (t < 128) ? v1 : v2;
        const float s = g[c] * rsqrtf(v[c] + BN_EPS);
        bnAs[t] = s; bnAb[t] = b[c] - m[c]*s;
    }
    {
        const float *g = (t < 128) ? g3 : g4, *b = (t < 128) ? b3 : b4;
        const float *m = (t < 128) ? m3 : m4, *v = (t < 128) ? v3 : v4;
        const float s = g[c] * rsqrtf(v[c] + BN_EPS);
        bnBs[t] = s; bnBb[t] = b[c] - m[c]*s;
    }
}

// ------- prep: x -> fp16 halo'd conv layout [row][32 chunk][66 slot][16 ch] --
__global__ __launch_bounds__(256)
void k_prep_x(const float* __restrict__ x, _Float16* __restrict__ xcv)
{
    __shared__ float Xl[16*520];
    const int t = threadIdx.x;
    const int pb = blockIdx.x * 16;           // 1024 blocks; 16 px of one row
    #pragma unroll
    for (int i = 0; i < 8; ++i) {
        const int u = t + i*256;
        const int px = u >> 7, c4 = (u & 127) * 4;
        *(float4*)&Xl[px*520 + c4] = *(const float4*)&x[(size_t)(pb + px)*CIN + c4];
    }
    __syncthreads();
    const int rowg = pb >> 6, pixb = pb & 63;
    #pragma unroll
    for (int i = 0; i < 8; ++i) {
        const int u = t + i*256;
        const int chunk = u >> 6, rem = u & 63;
        const int pl = rem >> 2, u4 = rem & 3;
        const float* src = &Xl[pl*520 + chunk*16 + u4*4];
        uint2 v;
        v.x = pkh2(src[0], src[1]);
        v.y = pkh2(src[2], src[3]);
        *(uint2*)&xcv[(((size_t)rowg*32 + chunk)*XSL + (pixb + pl + 1))*16 + u4*4] = v;
    }
    // zero the halo slots (0 and 65) of every chunk page of this row
    if (pixb == 0 && t < 64) {
        const int chunk = t >> 1, sl = (t & 1) * 65;
        uint4* dst = (uint4*)&xcv[(((size_t)rowg*32 + chunk)*XSL + sl)*16];
        uint4 z; z.x = 0u; z.y = 0u; z.z = 0u; z.w = 0u;
        dst[0] = z; dst[1] = z;
    }
}

// ---- zero halo slots of saf_h/scf_h (run AFTER conv1: region aliases xcv) ---
__global__ __launch_bounds__(256)
void k_zhalo(_Float16* __restrict__ saf_h, _Float16* __restrict__ scf_h)
{
    const int idx = blockIdx.x * 256 + threadIdx.x;   // 8192 units
    if (idx >= 8192) return;
    _Float16* arr = (idx & 4096) ? scf_h : saf_h;
    const int rem = idx & 4095;
    const int row = rem >> 4, chunk = (rem >> 1) & 7, sl = (rem & 1) * 65;
    uint4* dst = (uint4*)&arr[(((size_t)row*8 + chunk)*XSL + sl)*16];
    uint4 z; z.x = 0u; z.y = 0u; z.z = 0u; z.w = 0u;
    dst[0] = z; dst[1] = z;
}

// ---------------- MFMA 3x3 conv, fp16, 4-row block, W+X LDS-staged -----------
template<int NCHNK, int NCOTOT, int WCOBASE>
__global__ __launch_bounds__(512)
void k_convr(const _Float16* __restrict__ xcv0, const _Float16* __restrict__ xcv1,
             const _Float16* __restrict__ wtF0, const _Float16* __restrict__ wtF1,
             const float* __restrict__ bnS, const float* __restrict__ bnBi,
             float* __restrict__ out0, float* __restrict__ out1)
{
    constexpr int WU4  = 1152;                // 9 taps * 128 u4 (18432 B)
    constexpr int XU4  = 792;                 // 6 pages * 132 u4 (12672 B)
    constexpr int BUFB = (WU4 + XU4) * 16;    // 31104 B per buffer
    __shared__ __align__(16) char Ls[2*BUFB];

    const int t     = threadIdx.x;
    const int wgid  = blockIdx.x;             // 256
    const int slice = wgid & 3;
    const int rg    = wgid >> 2;              // 0..63 (4-row group)
    const int sel   = slice >> 1;
    const int ch2   = slice & 1;
    const _Float16* xcv = sel ? xcv1 : xcv0;
    const _Float16* wtF = sel ? wtF1 : wtF0;
    float* dst = sel ? out1 : out0;

    const int hh0 = (rg*4) & 63;              // row-in-image of group start
    const int l = t & 63, w = t >> 6;
    const int lo5 = l & 31, hf = l >> 5;
    const int r = w >> 1, mi = w & 1;
    const int cobase0 = WCOBASE*sel + ch2*64;

    // ---- hoisted stage decode: 1944 u4 units, 4 slots/thread ----
    bool sAct[4]; bool sIsW[4]; int sDst[4]; size_t sSrc[4]; unsigned sStr[4];
    #pragma unroll
    for (int i = 0; i < 4; ++i) {
        const int u = t + i*512;
        sAct[i] = false; sIsW[i] = false; sDst[i] = -1; sSrc[i] = 0; sStr[i] = 0;
        if (u < WU4) {
            const int tap = u >> 7, rem = u & 127;
            const int co = rem >> 1, whf = rem & 1;
            sAct[i] = true; sIsW[i] = true;
            sSrc[i] = (size_t)(tap*NCOTOT + cobase0 + co)*32 + whf*16;
            sStr[i] = (unsigned)(9*NCOTOT*32);
            sDst[i] = (tap*128 + whf*64 + co) * 16;
        } else if (u < WU4 + XU4) {
            const int j = u - WU4;
            const int page = j / 132, rem132 = j - page*132;
            const int slot = rem132 >> 1, xhf = rem132 & 1;
            const int hin = hh0 + page - 1;               // row in image
            sAct[i] = (hin >= 0 && hin < Hn);
            const int gr = rg*4 + page - 1;               // global row
            sSrc[i] = (size_t)gr*NCHNK*2112 + (size_t)(slot*32 + xhf*16);
            sStr[i] = 2112u;
            sDst[i] = WU4*16 + page*2112 + ((slot*32 + xhf*16) ^ ((slot & 7) << 4));
        }
    }
    // hoisted compute X offsets (dy, dx) for this wave's (r, mi)
    int xoff[3][3];
    #pragma unroll
    for (int dy = 0; dy < 3; ++dy)
        #pragma unroll
        for (int dx = 0; dx < 3; ++dx) {
            const int s = mi*32 + lo5 + dx;
            xoff[dy][dx] = WU4*16 + (r + dy)*2112 + ((s*32 + hf*16) ^ ((s & 7) << 4));
        }

    f32x16 acc[2];
    acc[0] = f16z(); acc[1] = f16z();

    uint4 xr[4];
    auto loadS = [&](int c) {
        #pragma unroll
        for (int i = 0; i < 4; ++i) {
            uint4 v; v.x = 0u; v.y = 0u; v.z = 0u; v.w = 0u;
            if (sAct[i]) {
                const char* base = sIsW[i] ? (const char*)wtF : (const char*)xcv;
                v = *(const uint4*)(base + sSrc[i] + (size_t)c*sStr[i]);
            }
            xr[i] = v;
        }
    };

    loadS(0);
    int p = 0;
    for (int c = 0; c < NCHNK; ++c) {
        char* Lp = Ls + p*BUFB;
        #pragma unroll
        for (int i = 0; i < 4; ++i)
            if (sDst[i] >= 0) *(uint4*)(Lp + sDst[i]) = xr[i];
        __syncthreads();
        if (c + 1 < NCHNK) loadS(c + 1);
        // ---- compute: 9 taps, 2 co-tiles each ----
        #pragma unroll
        for (int dy = 0; dy < 3; ++dy)
            #pragma unroll
            for (int dx = 0; dx < 3; ++dx) {
                const half8 xf = *(const half8*)(Lp + xoff[dy][dx]);
                const half8 w0 = *(const half8*)(Lp + ((dy*3 + dx)*128 + hf*64 + lo5)*16);
                const half8 w1 = *(const half8*)(Lp + ((dy*3 + dx)*128 + hf*64 + 32 + lo5)*16);
                acc[0] = __builtin_amdgcn_mfma_f32_32x32x16_f16(w0, xf, acc[0], 0, 0, 0);
                acc[1] = __builtin_amdgcn_mfma_f32_32x32x16_f16(w1, xf, acc[1], 0, 0, 0);
            }
        p ^= 1;
    }
    // ---- epilogue: folded BN + ReLU (fp32 out) ----
    const int px = mi*32 + lo5;
    const size_t pg = (size_t)(rg*4 + r)*Wn + px;
    #pragma unroll
    for (int cot = 0; cot < 2; ++cot)
        #pragma unroll
        for (int rr = 0; rr < 16; ++rr) {
            const int crow = (rr & 3) + 8*(rr >> 2) + 4*hf;
            const int och = ch2*64 + cot*32 + crow;
            const int bnidx = sel*128 + och;
            dst[pg*CI + och] = fmaxf(fmaf(acc[cot][rr], bnS[bnidx], bnBi[bnidx]), 0.f);
        }
}

// ---------------- K2a: q,k 1x1 conv -> bf16 (q pre-scaled by log2e) ----------
__global__ __launch_bounds__(256)
void k_qk(const float* __restrict__ feat1,
          const float* __restrict__ wq, const float* __restrict__ bq,
          const float* __restrict__ wk, const float* __restrict__ bk,
          __hip_bfloat16* __restrict__ qb, __hip_bfloat16* __restrict__ kb)
{
    __shared__ float Al[64*129];
    __shared__ __align__(16) float Wl[128*32];
    const int t = threadIdx.x;
    const int pb = blockIdx.x * 64;
    for (int idx = t; idx < 64*128; idx += 256) {
        const int p = idx >> 7, ci = idx & 127;
        Al[p*129 + ci] = feat1[(size_t)(pb + p)*CI + ci];
    }
    for (int idx = t; idx < 128*32; idx += 256) {
        const int ci = idx >> 5, c = idx & 31;
        Wl[idx] = (c < 16) ? wq[ci*16 + c] : wk[ci*16 + (c - 16)];
    }
    __syncthreads();
    const int p = t & 63, cg = t >> 6, co = cg * 8;
    F8 acc = f8zero();
    #pragma unroll 8
    for (int ci = 0; ci < 128; ++ci) {
        const float a = Al[p*129 + ci];
        const float4 wlo = *(const float4*)&Wl[ci*32 + co];
        const float4 whi = *(const float4*)&Wl[ci*32 + co + 4];
        fma8(acc, a, wlo, whi);
    }
    const float* af = (const float*)&acc;
    #pragma unroll
    for (int j = 0; j < 8; ++j) {
        const int c = co + j;
        if (c < 16) qb[(size_t)(pb + p)*16 + c]        = __float2bfloat16((af[j] + bq[c]) * LOG2E);
        else        kb[(size_t)(pb + p)*16 + (c - 16)] = __float2bfloat16(af[j] + bk[c - 16]);
    }
}

// ---------------- K2b: v 1x1 conv -> bf16 COALESCED [b][key/16][c][16key] ----
__global__ __launch_bounds__(256)
void k_v(const float* __restrict__ feat1, const float* __restrict__ wv,
         const float* __restrict__ bv, __hip_bfloat16* __restrict__ vbT)
{
    __shared__ float Al[32*129];
    __shared__ __align__(16) float Wl[64*128];
    const int t = threadIdx.x;
    const int pb = blockIdx.x * 32;
    for (int idx = t; idx < 32*128; idx += 256) {
        const int p = idx >> 7, ci = idx & 127;
        Al[p*129 + ci] = feat1[(size_t)(pb + p)*CI + ci];
    }
    const int px = t & 15, co = (t >> 4) * 8;
    F8 acc0 = f8zero(), acc1 = f8zero();
    for (int ch = 0; ch < 2; ++ch) {
        __syncthreads();
        #pragma unroll
        for (int r = 0; r < 8; ++r) {
            const int i4 = t + r*256;
            const int kk = i4 >> 5, c4 = (i4 & 31) * 4;
            *(float4*)&Wl[kk*128 + c4] = *(const float4*)&wv[(size_t)(ch*64 + kk)*CI + c4];
        }
        __syncthreads();
        #pragma unroll 4
        for (int kk = 0; kk < 64; ++kk) {
            const float a0 = Al[px*129 + ch*64 + kk];
            const float a1 = Al[(px+16)*129 + ch*64 + kk];
            const float4 wlo = *(const float4*)&Wl[kk*128 + co];
            const float4 whi = *(const float4*)&Wl[kk*128 + co + 4];
            fma8(acc0, a0, wlo, whi);
            fma8(acc1, a1, wlo, whi);
        }
    }
    const int p0 = pb + px;
    const int bb = p0 / HWn, pin0 = p0 % HWn;
    const int k16a = pin0 >> 4, ko = pin0 & 15;
    const float* a0f = (const float*)&acc0;
    const float* a1f = (const float*)&acc1;
    #pragma unroll
    for (int j = 0; j < 8; ++j) {
        const int c = co + j;
        const size_t base = ((size_t)bb*256*CI*16) + (size_t)c*16 + ko;
        vbT[base + (size_t)k16a*CI*16]       = __float2bfloat16(a0f[j] + bv[c]);
        vbT[base + (size_t)(k16a + 1)*CI*16] = __float2bfloat16(a1f[j] + bv[c]);
    }
}

// ---------------- K3: PAM flash attention, 4-wave K-split, 2-tile ILP --------
// Two 64-key tiles per iteration with JOINT max/rescale/sum: 4 back-to-back
// QK MFMAs, one rescale check per 128 keys, 64 independent exp2, then PV for
// tile A (per-slice V loads, per-wave Ppk region reused) followed by tile B.
// hw exp2 + pointer-increment addressing (R22-validated).
__global__ __launch_bounds__(256)
void k_pam(const __hip_bfloat16* __restrict__ qb, const __hip_bfloat16* __restrict__ kb,
           const __hip_bfloat16* __restrict__ vbT, const float* __restrict__ feat1,
           const float* __restrict__ gamma, _Float16* __restrict__ saf_h)
{
    __shared__ __align__(16) char pbuf[16896];   // Ppk[4][1024 u32] -> osum[32][132] f32
    __shared__ float msArr[4][32];
    __shared__ float ssArr[4][32];
    __shared__ float ssum[32];
    const int t  = threadIdx.x;
    const int wv = t >> 6, l = t & 63;
    const int lo5 = l & 31, h = l >> 5;
    unsigned* Ppk = (unsigned*)(pbuf + wv*4096);
    float* osum = (float*)pbuf;

    // batch-pinned XCD decode (512 blocks: 128 per batch on 2 XCDs)
    const int wgid = blockIdx.x;
    const int xcd  = wgid & 7;
    const int bb   = xcd >> 1;                       // batch
    const int qt   = ((wgid >> 3) << 1) | (xcd & 1); // q-tile 0..127
    const int q0   = bb*HWn + qt*32;                 // global pixel row base
    const size_t jb = (size_t)bb * HWn;

    const short8 qfrag = *(const short8*)&qb[(size_t)(q0 + lo5)*16 + 8*h];
    const f32x16 zro = f16z();

    f32x16 o[4];
    #pragma unroll
    for (int cb = 0; cb < 4; ++cb) o[cb] = f16z();

    float m_run = -1e30f, s_run = 0.f;

    const int kbeg = wv*1024;
    // lane-base byte pointers, advanced by constant strides per pair
    const char* kp = (const char*)kb + (size_t)(jb + kbeg + lo5)*32 + 16*h;
    const char* vp = (const char*)vbT + (size_t)bb*256*CI*32
                     + ((size_t)(kbeg >> 4)*CI + lo5)*32 + 16*h;
    short8 kf0 = *(const short8*)kp;
    short8 kf1 = *(const short8*)(kp + 1024);
    short8 kf2 = *(const short8*)(kp + 2048);
    short8 kf3 = *(const short8*)(kp + 3072);
    kp += 4096;

    for (int it = 0; it < 8; ++it) {            // 8 x 128 keys = 1024
        f32x16 e0 = __builtin_amdgcn_mfma_f32_32x32x16_bf16(kf0, qfrag, zro, 0, 0, 0);
        f32x16 e1 = __builtin_amdgcn_mfma_f32_32x32x16_bf16(kf1, qfrag, zro, 0, 0, 0);
        f32x16 e2 = __builtin_amdgcn_mfma_f32_32x32x16_bf16(kf2, qfrag, zro, 0, 0, 0);
        f32x16 e3 = __builtin_amdgcn_mfma_f32_32x32x16_bf16(kf3, qfrag, zro, 0, 0, 0);

        // prefetch next pair's K fragments
        if (it + 1 < 8) {
            kf0 = *(const short8*)kp;
            kf1 = *(const short8*)(kp + 1024);
            kf2 = *(const short8*)(kp + 2048);
            kf3 = *(const short8*)(kp + 3072);
            kp += 4096;
        }

        // joint tree max over 64 values (depth ~6)
        float mx8[8];
        #pragma unroll
        for (int r = 0; r < 8; ++r)
            mx8[r] = fmaxf(fmaxf(fmaxf(e0[r], e0[r+8]), fmaxf(e1[r], e1[r+8])),
                           fmaxf(fmaxf(e2[r], e2[r+8]), fmaxf(e3[r], e3[r+8])));
        mx8[0] = fmaxf(mx8[0], mx8[4]);
        mx8[1] = fmaxf(mx8[1], mx8[5]);
        mx8[2] = fmaxf(mx8[2], mx8[6]);
        mx8[3] = fmaxf(mx8[3], mx8[7]);
        mx8[0] = fmaxf(mx8[0], mx8[2]);
        mx8[1] = fmaxf(mx8[1], mx8[3]);
        float mt = fmaxf(mx8[0], mx8[1]);
        mt = fmaxf(mt, __shfl_xor(mt, 32));

        if (__any(mt > m_run + 11.5416f)) {   // 8 * log2(e)
            const float mnew = fmaxf(m_run, mt);
            const float sc = ex2(m_run - mnew);
            s_run *= sc;
            #pragma unroll
            for (int cb = 0; cb < 4; ++cb)
                #pragma unroll
                for (int r = 0; r < 16; ++r) o[cb][r] *= sc;
            m_run = mnew;
        }

        #pragma unroll
        for (int r = 0; r < 16; ++r) {
            e0[r] = ex2(e0[r] - m_run);
            e1[r] = ex2(e1[r] - m_run);
            e2[r] = ex2(e2[r] - m_run);
            e3[r] = ex2(e3[r] - m_run);
        }
        // joint tree sum
        {
            float s8[8];
            #pragma unroll
            for (int r = 0; r < 8; ++r)
                s8[r] = ((e0[r] + e0[r+8]) + (e1[r] + e1[r+8]))
                      + ((e2[r] + e2[r+8]) + (e3[r] + e3[r+8]));
            s8[0] += s8[4]; s8[1] += s8[5]; s8[2] += s8[6]; s8[3] += s8[7];
            s8[0] += s8[2]; s8[1] += s8[3];
            s_run += s8[0] + s8[1];
        }

        // ---- tile A: pack P, PV (per-slice V loads) ----
        #pragma unroll
        for (int r = 0; r < 16; r += 2) {
            const int pidx = ((r & 3) >> 1) + 4*(r >> 2) + 2*h;
            Ppk[pidx*32 + lo5]        = pkb2(e0[r], e0[r+1]);
            Ppk[(16 + pidx)*32 + lo5] = pkb2(e1[r], e1[r+1]);
        }
        #pragma unroll
        for (int s = 0; s < 4; ++s) {
            union { unsigned u[4]; short8 s8; } P;
            #pragma unroll
            for (int w = 0; w < 4; ++w)
                P.u[w] = Ppk[(s*8 + 4*h + w)*32 + lo5];
            #pragma unroll
            for (int cb = 0; cb < 4; ++cb) {
                const short8 vf = *(const short8*)(vp + s*4096 + cb*1024);
                o[cb] = __builtin_amdgcn_mfma_f32_32x32x16_bf16(vf, P.s8, o[cb], 0, 0, 0);
            }
        }
        // ---- tile B: pack P, PV ----
        #pragma unroll
        for (int r = 0; r < 16; r += 2) {
            const int pidx = ((r & 3) >> 1) + 4*(r >> 2) + 2*h;
            Ppk[pidx*32 + lo5]        = pkb2(e2[r], e2[r+1]);
            Ppk[(16 + pidx)*32 + lo5] = pkb2(e3[r], e3[r+1]);
        }
        #pragma unroll
        for (int s = 0; s < 4; ++s) {
            union { unsigned u[4]; short8 s8; } P;
            #pragma unroll
            for (int w = 0; w < 4; ++w)
                P.u[w] = Ppk[(s*8 + 4*h + w)*32 + lo5];
            #pragma unroll
            for (int cb = 0; cb < 4; ++cb) {
                const short8 vf = *(const short8*)(vp + 16384 + s*4096 + cb*1024);
                o[cb] = __builtin_amdgcn_mfma_f32_32x32x16_bf16(vf, P.s8, o[cb], 0, 0, 0);
            }
        }
        vp += 32768;
    }

    // ---- publish per-wave (m, s) ----
    const float s_w = s_run + __shfl_xor(s_run, 32);
    if (h == 0) { msArr[wv][lo5] = m_run; ssArr[wv][lo5] = s_w; }
    __syncthreads();                          // all waves done with Ppk too

    // ---- merge ----
    float M = msArr[0][lo5];
    #pragma unroll
    for (int w = 1; w < 4; ++w) M = fmaxf(M, msArr[w][lo5]);
    float stot = 0.f;
    #pragma unroll
    for (int w = 0; w < 4; ++w) stot += ex2(msArr[w][lo5] - M) * ssArr[w][lo5];
    if (wv == 0 && h == 0) ssum[lo5] = stot;
    const float myscale = ex2(m_run - M);
    #pragma unroll
    for (int cb = 0; cb < 4; ++cb)
        #pragma unroll
        for (int r = 0; r < 16; ++r) o[cb][r] *= myscale;

    for (int w = 0; w < 4; ++w) {
        if (wv == w) {
            #pragma unroll
            for (int cb = 0; cb < 4; ++cb)
                #pragma unroll
                for (int r = 0; r < 16; ++r) {
                    const int c = cb*32 + (r & 3) + 8*(r >> 2) + 4*h;
                    float* p = &osum[lo5*132 + c];
                    if (w == 0) *p = o[cb][r]; else *p += o[cb][r];
                }
        }
        __syncthreads();
    }

    // ---- normalize + residual, write fp16 halo'd conv layout ----
    const float g = gamma[0];
    const int qloc = t >> 3, ch8 = t & 7;
    const float inv = 1.f / ssum[qloc];
    const int pgl = q0 + qloc;
    const int rowp = pgl >> 6, pixp = pgl & 63;
    const size_t gbase = (size_t)pgl*CI + ch8*16;
    union { _Float16 hv[16]; uint4 u[2]; } tmp;
    #pragma unroll
    for (int j = 0; j < 16; ++j)
        tmp.hv[j] = (_Float16)(g*(osum[qloc*132 + ch8*16 + j]*inv) + feat1[gbase + j]);
    uint4* dsth = (uint4*)&saf_h[(((size_t)rowp*8 + ch8)*XSL + (pixp + 1))*16];
    dsth[0] = tmp.u[0];
    dsth[1] = tmp.u[1];
}

// ---------------- K4x: transpose feat2 -> bf16 hi/lo [b][c][HW] --------------
__global__ __launch_bounds__(256)
void k_xpose(const float* __restrict__ feat2,
             char* __restrict__ f2TH, char* __restrict__ f2TL)
{
    __shared__ float Xl[64*129];
    const int t = threadIdx.x;
    const int pb = blockIdx.x * 64;
    const int bb = pb / HWn, pin = pb % HWn;
    for (int idx = t; idx < 64*128; idx += 256) {
        const int p = idx >> 7, ci = idx & 127;
        Xl[p*129 + ci] = feat2[(size_t)(pb + p)*CI + ci];
    }
    __syncthreads();
    const int c = t >> 1, half = t & 1;
    const size_t rowb = ((size_t)(bb*CI + c)*HWn + pin + half*32) * 2;
    #pragma unroll
    for (int j = 0; j < 16; ++j) {
        const float a = Xl[(half*32 + 2*j)*129 + c];
        const float b = Xl[(half*32 + 2*j + 1)*129 + c];
        unsigned hi, lo; split2(a, b, hi, lo);
        *(unsigned*)(f2TH + rowb + 4*j) = hi;
        *(unsigned*)(f2TL + rowb + 4*j) = lo;
    }
}

// ---------------- K4a: CAM energy via MFMA, split-K partials -----------------
__global__ __launch_bounds__(256)
void k_cam_energy_m(const char* __restrict__ f2TH, const char* __restrict__ f2TL,
                    float* __restrict__ epart)
{
    __shared__ __align__(16) char Vh[128*256];
    __shared__ __align__(16) char Vl[128*256];
    const int t = threadIdx.x;
    const int ks = blockIdx.x, bb = blockIdx.y;
    const int l = t & 63, w = t >> 6;
    const int lo5 = l & 31, hf = l >> 5;

    #pragma unroll
    for (int pass = 0; pass < 8; ++pass) {
        const int slot = pass*256 + t;
        const int c = slot >> 4, g = slot & 15;
        const size_t gaddr = ((size_t)(bb*CI + c)*HWn + ks*128)*2 + g*16;
        const int laddr = c*256 + ((g*16) ^ ((c & 15) << 4));
        *(float4*)(Vh + laddr) = *(const float4*)(f2TH + gaddr);
        *(float4*)(Vl + laddr) = *(const float4*)(f2TL + gaddr);
    }
    __syncthreads();

    f32x16 acc[4];
    #pragma unroll
    for (int nj = 0; nj < 4; ++nj) acc[nj] = f16z();
    const int cA = w*32 + lo5;
    const int swA = (cA & 15) << 4;

    #pragma unroll
    for (int kk = 0; kk < 8; ++kk) {
        const int kb = kk*32 + hf*16;
        const short8 ah = *(const short8*)(Vh + cA*256 + (kb ^ swA));
        const short8 al = *(const short8*)(Vl + cA*256 + (kb ^ swA));
        #pragma unroll
        for (int nj = 0; nj < 4; ++nj) {
            const int dB = nj*32 + lo5;
            const int swB = (dB & 15) << 4;
            const short8 bh = *(const short8*)(Vh + dB*256 + (kb ^ swB));
            const short8 bl = *(const short8*)(Vl + dB*256 + (kb ^ swB));
            acc[nj] = __builtin_amdgcn_mfma_f32_32x32x16_bf16(ah, bh, acc[nj], 0, 0, 0);
            acc[nj] = __builtin_amdgcn_mfma_f32_32x32x16_bf16(al, bh, acc[nj], 0, 0, 0);
            acc[nj] = __builtin_amdgcn_mfma_f32_32x32x16_bf16(ah, bl, acc[nj], 0, 0, 0);
        }
    }
    float* ep = epart + ((size_t)(bb*32 + ks)*CI)*CI;
    #pragma unroll
    for (int nj = 0; nj < 4; ++nj)
        #pragma unroll
        for (int r = 0; r < 16; ++r) {
            const int c = w*32 + (r & 3) + 8*(r >> 2) + 4*hf;
            ep[(size_t)c*CI + nj*32 + lo5] = acc[nj][r];
        }
}

// ---------------- K4b: fused reduce + max-subtract softmax -------------------
__global__ __launch_bounds__(64)
void k_cam_rs(const float* __restrict__ epart, float* __restrict__ att)
{
    const int lane = threadIdx.x;
    const int row = blockIdx.x;             // b*128 + c
    const int bb = row >> 7, c = row & 127;
    float2 e = make_float2(0.f, 0.f);
    for (int ks = 0; ks < 32; ++ks) {
        const float2 v = *(const float2*)&epart[
            ((size_t)(bb*32 + ks)*CI + c)*CI + lane*2];
        e.x += v.x; e.y += v.y;
    }
    float M = fmaxf(e.x, e.y);
    #pragma unroll
    for (int off = 32; off > 0; off >>= 1) M = fmaxf(M, __shfl_xor(M, off));
    const float en0 = M - e.x, en1 = M - e.y;
    float mx = fmaxf(en0, en1);
    #pragma unroll
    for (int off = 32; off > 0; off >>= 1) mx = fmaxf(mx, __shfl_xor(mx, off));
    const float p0 = __expf(en0 - mx), p1 = __expf(en1 - mx);
    float s = p0 + p1;
    #pragma unroll
    for (int off = 32; off > 0; off >>= 1) s += __shfl_xor(s, off);
    const float inv = 1.f / s;
    float2 o; o.x = p0*inv; o.y = p1*inv;
    *(float2*)&att[(size_t)row*CI + lane*2] = o;
}

// ---------------- K4c: CAM apply -> fp16 halo'd conv layout ------------------
__global__ __launch_bounds__(256)
void k_cam_apply(const float* __restrict__ feat2, const float* __restrict__ att,
                 const float* __restrict__ gamma, _Float16* __restrict__ scf_h)
{
    __shared__ float Xl[64*129];
    __shared__ __align__(16) float aT[128*64];
    const int t = threadIdx.x;
    const int pb = blockIdx.x * 64;
    const int bb = pb / HWn;
    const int ch = blockIdx.y * 64;
    for (int idx = t; idx < 64*128; idx += 256) {
        const int p = idx >> 7, ci = idx & 127;
        Xl[p*129 + ci] = feat2[(size_t)(pb + p)*CI + ci];
    }
    for (int idx = t; idx < 128*64; idx += 256) {
        const int d = idx >> 6, cc = idx & 63;
        aT[d*64 + cc] = att[((size_t)bb*CI + ch + cc)*CI + d];
    }
    __syncthreads();
    const int px = t & 63, cg = t >> 6;
    F8 accA = f8zero(), accB = f8zero();
    #pragma unroll 4
    for (int d = 0; d < 128; ++d) {
        const float xv = Xl[px*129 + d];
        const float* ap = &aT[d*64 + cg*16];
        const float4 a0 = *(const float4*)&ap[0];
        const float4 a1 = *(const float4*)&ap[4];
        const float4 a2 = *(const float4*)&ap[8];
        const float4 a3 = *(const float4*)&ap[12];
        fma8(accA, xv, a0, a1);
        fma8(accB, xv, a2, a3);
    }
    const float g = gamma[0];
    const float* fa = (const float*)&accA;
    const float* fb = (const float*)&accB;
    const int p0g = pb + px;
    const int rowA = p0g >> 6, pixA = p0g & 63;
    const int chunkA = (ch >> 4) + cg;
    const size_t baseA = (((size_t)rowA*8 + chunkA)*XSL + (pixA + 1))*16;
    #pragma unroll
    for (int j = 0; j < 8; ++j) {
        const int cA = ch + cg*16 + j;
        const int cB = cA + 8;
        scf_h[baseA + j]     = (_Float16)(g*fa[j] + Xl[px*129 + cA]);
        scf_h[baseA + 8 + j] = (_Float16)(g*fb[j] + Xl[px*129 + cB]);
    }
}

// ---------------- K7: final 1x1 conv (sum of two branches) -> out ------------
__global__ __launch_bounds__(256)
void k_final(const float* __restrict__ sa, const float* __restrict__ sc,
             const float* __restrict__ w8, float* __restrict__ out)
{
    __shared__ float Xl[64*129];
    __shared__ float w8l[128*COn];
    const int t = threadIdx.x;
    const int pb = blockIdx.x * 64;
    for (int idx = t; idx < 64*128; idx += 256) {
        const int p = idx >> 7, ci = idx & 127;
        const size_t gi = (size_t)(pb + p)*CI + ci;
        Xl[p*129 + ci] = sa[gi] + sc[gi];
    }
    for (int idx = t; idx < 128*COn; idx += 256) w8l[idx] = w8[idx];
    __syncthreads();
    for (int idx = t; idx < 64*COn; idx += 256) {
        const int p = idx / COn, co = idx - p*COn;
        float acc = 0.f;
        #pragma unroll 8
        for (int ci = 0; ci < 128; ++ci)
            acc = fmaf(Xl[p*129 + ci], w8l[ci*COn + co], acc);
        out[(size_t)(pb + p)*COn + co] = acc;
    }
}

extern "C" void kernel_launch(void* const* d_in, const int* in_sizes, int n_in,
                              void* d_out, int out_size, void* d_ws, size_t ws_size,
                              hipStream_t stream)
{
    const float* x    = (const float*)d_in[0];
    const float* w5a  = (const float*)d_in[1];
    const float* w5c  = (const float*)d_in[2];
    const float* wq   = (const float*)d_in[3];
    const float* bq   = (const float*)d_in[4];
    const float* wk   = (const float*)d_in[5];
    const float* bk   = (const float*)d_in[6];
    const float* wv   = (const float*)d_in[7];
    const float* bv   = (const float*)d_in[8];
    const float* pgam = (const float*)d_in[9];
    const float* cgam = (const float*)d_in[10];
    const float* w51  = (const float*)d_in[11];
    const float* w52  = (const float*)d_in[12];
    const float* w8   = (const float*)d_in[13];
    const float* bn1g = (const float*)d_in[14];
    const float* bn1b = (const float*)d_in[15];
    const float* bn1m = (const float*)d_in[16];
    const float* bn1v = (const float*)d_in[17];
    const float* bn2g = (const float*)d_in[18];
    const float* bn2b = (const float*)d_in[19];
    const float* bn2m = (const float*)d_in[20];
    const float* bn2v = (const float*)d_in[21];
    const float* bn3g = (const float*)d_in[22];
    const float* bn3b = (const float*)d_in[23];
    const float* bn3m = (const float*)d_in[24];
    const float* bn3v = (const float*)d_in[25];
    const float* bn4g = (const float*)d_in[26];
    const float* bn4b = (const float*)d_in[27];
    const float* bn4m = (const float*)d_in[28];
    const float* bn4v = (const float*)d_in[29];

    char* wsb = (char*)d_ws;
    float* feat1 = (float*)(wsb + 0);
    char*  f2TH  = wsb + 0;                     // 4 MB
    char*  f2TL  = wsb + 4194304;               // 4 MB
    float* feat2 = (float*)(wsb + 8388608);
    _Float16* xcv   = (_Float16*)(wsb + 16777216);   // 17,301,504 B
    _Float16* saf_h = (_Float16*)(wsb + 16777216);   // 4,325,376 B (post-conv1)
    _Float16* scf_h = (_Float16*)(wsb + 21102592);   // 4,325,376 B -> 25427968
    float*    epart = (float*)(wsb + 25427968);      // 8 MB -> 33816576
    float* att = (float*)(wsb + 33816576);           // 256 KB -> 34078720
    __hip_bfloat16* qb16 = (__hip_bfloat16*)(wsb + 34078720);  // 512 KB
    __hip_bfloat16* kb16 = (__hip_bfloat16*)(wsb + 34603008);  // 512 KB
    __hip_bfloat16* vbT  = (__hip_bfloat16*)(wsb + 35127296);  // 4 MB -> 39321600
    char* wt1F  = wsb + 39321600;               // 2359296 -> 41680896
    char* wt2aF = wsb + 41680896;               // 294912  -> 41975808
    char* wt2bF = wsb + 41975808;               // 294912  -> 42270720
    float* bnAs = (float*)(wsb + 42270720);
    float* bnAb = (float*)(wsb + 42271744);
    float* bnBs = (float*)(wsb + 42272768);
    float* bnBb = (float*)(wsb + 42273792);     // high-water 42274816
    float* sa_conv = feat1;
    float* sc_conv = feat2;
    float* out  = (float*)d_out;

    k_prep_w<<<dim3(2880), 256, 0, stream>>>(w5a, w5c, w51, w52, wt1F, wt2aF, wt2bF);
    k_prep_bn<<<dim3(1), 256, 0, stream>>>(bn1g, bn1b, bn1m, bn1v, bn2g, bn2b, bn2m, bn2v,
                                           bn3g, bn3b, bn3m, bn3v, bn4g, bn4b, bn4m, bn4v,
                                           bnAs, bnAb, bnBs, bnBb);
    k_prep_x<<<dim3(1024), 256, 0, stream>>>(x, xcv);
    k_convr<32, 256, 128><<<dim3(256), 512, 0, stream>>>(
        xcv, xcv, (const _Float16*)wt1F, (const _Float16*)wt1F, bnAs, bnAb, feat1, feat2);
    k_zhalo<<<dim3(32), 256, 0, stream>>>(saf_h, scf_h);   // after conv1: aliases xcv
    k_qk<<<dim3(NPIX/64), 256, 0, stream>>>(feat1, wq, bq, wk, bk, qb16, kb16);
    k_v<<<dim3(NPIX/32), 256, 0, stream>>>(feat1, wv, bv, vbT);
    k_pam<<<dim3(NPIX/32), 256, 0, stream>>>(qb16, kb16, vbT, feat1, pgam, saf_h);
    k_xpose<<<dim3(NPIX/64), 256, 0, stream>>>(feat2, f2TH, f2TL);
    k_cam_energy_m<<<dim3(32, Bn), 256, 0, stream>>>(f2TH, f2TL, epart);
    k_cam_rs<<<dim3(Bn*CI), 64, 0, stream>>>(epart, att);
    k_cam_apply<<<dim3(NPIX/64, 2), 256, 0, stream>>>(feat2, att, cgam, scf_h);
    k_convr<8, 128, 0><<<dim3(256), 512, 0, stream>>>(
        saf_h, scf_h, (const _Float16*)wt2aF, (const _Float16*)wt2bF,
        bnBs, bnBb, sa_conv, sc_conv);
    k_final<<<dim3(NPIX/64), 256, 0, stream>>>(sa_conv, sc_conv, w8, out);
}